// Round 1
// baseline (2094.650 us; speedup 1.0000x reference)
//
#include <hip/hip_runtime.h>
#include <math.h>

#define B_ 2
#define L_ 1024
#define DM 256
#define NL_ 6
#define DI_ 512
#define DS_ 16
#define DC_ 4
#define NC_ 10
#define ALPHA_ 0.1f

__device__ __forceinline__ float sigmoidf_(float x){ return 1.f/(1.f+__expf(-x)); }

// ---------------- embed: h = emb[x] + pos_emb[:L] ----------------
__global__ void k_embed(const float* __restrict__ emb, const float* __restrict__ pos,
                        const int* __restrict__ ids, float* __restrict__ h){
  int row = blockIdx.x;            // 0..B*L-1
  int t = row & (L_-1);
  int d = threadIdx.x;             // 0..255
  int v = ids[row];
  h[(size_t)row*DM + d] = emb[(size_t)v*DM + d] + pos[(size_t)t*DM + d];
}

// ---------------- layernorm over rows of 256 ----------------
__global__ void k_ln(const float* __restrict__ x, float* __restrict__ y,
                     const float* __restrict__ w, const float* __restrict__ b){
  int row = blockIdx.x;
  int d = threadIdx.x;
  float v = x[(size_t)row*DM + d];
  float s1 = v, s2 = v*v;
  #pragma unroll
  for (int o=32;o>0;o>>=1){ s1 += __shfl_down(s1,o); s2 += __shfl_down(s2,o); }
  __shared__ float a1[4], a2[4];
  __shared__ float mv[2];
  int wid = d>>6, lane = d&63;
  if (lane==0){ a1[wid]=s1; a2[wid]=s2; }
  __syncthreads();
  if (d==0){
    float t1=a1[0]+a1[1]+a1[2]+a1[3];
    float t2=a2[0]+a2[1]+a2[2]+a2[3];
    float m = t1/(float)DM;
    float var = t2/(float)DM - m*m;
    mv[0]=m; mv[1]=rsqrtf(var+1e-5f);
  }
  __syncthreads();
  y[(size_t)row*DM+d] = (v - mv[0])*mv[1]*w[d] + b[d];
}

// ---------------- C[M,N] = A[M,K] @ W[N,K]^T (+RES) ----------------
template<bool ADD_RES>
__global__ void k_gemm(const float* __restrict__ A, const float* __restrict__ W,
                       const float* __restrict__ RES, float* __restrict__ C,
                       int M, int N, int K){
  const int BM=64, BN=64, BK=16;
  __shared__ float As[BK][BM];
  __shared__ float Ws[BK][BN];
  int bm = blockIdx.y*BM, bn = blockIdx.x*BN;
  int tid = threadIdx.x;           // 256
  int tx = tid & 15, ty = tid >> 4;
  int lr = tid >> 2, lc4 = (tid & 3) << 2;
  float acc[4][4] = {};
  for (int k0=0;k0<K;k0+=BK){
    float4 av = *reinterpret_cast<const float4*>(&A[(size_t)(bm+lr)*K + k0 + lc4]);
    float4 wv = *reinterpret_cast<const float4*>(&W[(size_t)(bn+lr)*K + k0 + lc4]);
    As[lc4+0][lr]=av.x; As[lc4+1][lr]=av.y; As[lc4+2][lr]=av.z; As[lc4+3][lr]=av.w;
    Ws[lc4+0][lr]=wv.x; Ws[lc4+1][lr]=wv.y; Ws[lc4+2][lr]=wv.z; Ws[lc4+3][lr]=wv.w;
    __syncthreads();
    #pragma unroll
    for (int k=0;k<BK;k++){
      float4 a4 = *reinterpret_cast<const float4*>(&As[k][ty*4]);
      float4 b4 = *reinterpret_cast<const float4*>(&Ws[k][tx*4]);
      float a[4]={a4.x,a4.y,a4.z,a4.w}, bb[4]={b4.x,b4.y,b4.z,b4.w};
      #pragma unroll
      for (int i=0;i<4;i++)
        #pragma unroll
        for (int j=0;j<4;j++)
          acc[i][j] = fmaf(a[i], bb[j], acc[i][j]);
    }
    __syncthreads();
  }
  #pragma unroll
  for (int i=0;i<4;i++){
    int r = bm + ty*4 + i;
    #pragma unroll
    for (int j=0;j<4;j++){
      int c = bn + tx*4 + j;
      float v = acc[i][j];
      if (ADD_RES) v += RES[(size_t)r*N + c];
      C[(size_t)r*N + c] = v;
    }
  }
}

// ---------------- causal depthwise conv (DC=4) + SiLU ----------------
__global__ void k_conv(const float* __restrict__ xz, const float* __restrict__ cw,
                       const float* __restrict__ cb, float* __restrict__ xc){
  int gid = blockIdx.x*blockDim.x + threadIdx.x; // B*L*DI
  int d = gid & (DI_-1);
  int m = gid >> 9;
  int t = m & (L_-1);
  float acc = cb[d];
  #pragma unroll
  for (int k=0;k<DC_;k++){
    int tt = t - 3 + k;
    if (tt >= 0)
      acc = fmaf(cw[d*DC_+k], xz[(size_t)(m-3+k)*(2*DI_) + d], acc);
  }
  xc[gid] = acc * sigmoidf_(acc);
}

// ---------------- x_proj (48x512) + dt_proj (512x16) + softplus ----------------
__global__ void k_xproj_dt(const float* __restrict__ xc, const float* __restrict__ xw,
                           const float* __restrict__ dtw, const float* __restrict__ dtb,
                           float* __restrict__ xdbl, float* __restrict__ delta){
  int m = blockIdx.x;
  int tid = threadIdx.x;
  __shared__ float sx[DI_];
  __shared__ float sp[48][4];
  __shared__ float sd[16];
  if (tid < 128)
    *reinterpret_cast<float4*>(&sx[tid*4]) =
      *reinterpret_cast<const float4*>(&xc[(size_t)m*DI_ + tid*4]);
  __syncthreads();
  if (tid < 192){
    int o = tid >> 2, p = tid & 3;
    const float* w = &xw[(size_t)o*DI_ + p*128];
    const float* xs = &sx[p*128];
    float acc = 0.f;
    #pragma unroll 8
    for (int k=0;k<128;k++) acc = fmaf(xs[k], w[k], acc);
    sp[o][p] = acc;
  }
  __syncthreads();
  if (tid < 48){
    float v = sp[tid][0]+sp[tid][1]+sp[tid][2]+sp[tid][3];
    xdbl[(size_t)m*48 + tid] = v;
    if (tid < 16) sd[tid] = v;
  }
  __syncthreads();
  for (int n=tid; n<DI_; n+=256){
    float acc = dtb[n];
    #pragma unroll
    for (int k=0;k<16;k++) acc = fmaf(sd[k], dtw[n*16+k], acc);
    delta[(size_t)m*DI_ + n] = (acc > 20.f) ? acc : log1pf(__expf(acc));
  }
}

// ---------------- selective scan + Luenberger + gate ----------------
// one lane per (b,d,n); 16-lane groups reduce y over n; LDS double-buffered chunks
__global__ void k_scan(const float* __restrict__ delta, const float* __restrict__ xc,
                       const float* __restrict__ xdbl, const float* __restrict__ xz,
                       const float* __restrict__ A_log, const float* __restrict__ Dp,
                       float* __restrict__ y2){
  const int TC = 64;
  __shared__ float sdel[2][TC][16];
  __shared__ float sxv [2][TC][16];
  __shared__ float sB  [2][TC][16];
  __shared__ float sC  [2][TC][16];
  __shared__ float sz  [2][TC][16];
  int tid = threadIdx.x;
  int n = tid & 15, dg = tid >> 4;
  int blk = blockIdx.x;
  int b = blk >> 5;
  int d0 = (blk & 31) << 4;
  int d = d0 + dg;
  float a = -__expf(A_log[(size_t)d*DS_ + n]);
  float dpv = Dp[d];
  int lrow = tid >> 2, lc4 = (tid & 3) << 2;
  float hs = 0.f, hh = 0.f;
  float4 rdel, rxc, rB, rC, rz;
  auto LOADR = [&](int ch){
    int mrow = b*L_ + ch*TC + lrow;
    rdel = *reinterpret_cast<const float4*>(&delta[(size_t)mrow*DI_ + d0 + lc4]);
    rxc  = *reinterpret_cast<const float4*>(&xc  [(size_t)mrow*DI_ + d0 + lc4]);
    rB   = *reinterpret_cast<const float4*>(&xdbl[(size_t)mrow*48 + 16 + lc4]);
    rC   = *reinterpret_cast<const float4*>(&xdbl[(size_t)mrow*48 + 32 + lc4]);
    rz   = *reinterpret_cast<const float4*>(&xz  [(size_t)mrow*(2*DI_) + DI_ + d0 + lc4]);
  };
  auto WRITE = [&](int bf){
    *reinterpret_cast<float4*>(&sdel[bf][lrow][lc4]) = rdel;
    *reinterpret_cast<float4*>(&sxv [bf][lrow][lc4]) = rxc;
    *reinterpret_cast<float4*>(&sB  [bf][lrow][lc4]) = rB;
    *reinterpret_cast<float4*>(&sC  [bf][lrow][lc4]) = rC;
    *reinterpret_cast<float4*>(&sz  [bf][lrow][lc4]) = rz;
  };
  LOADR(0); WRITE(0); __syncthreads();
  int buf = 0;
  for (int ch=0; ch<L_/TC; ++ch){
    if (ch < L_/TC-1) LOADR(ch+1);
    int mbase = b*L_ + ch*TC;
    #pragma unroll 4
    for (int t=0;t<TC;t++){
      float dv = sdel[buf][t][dg];
      float xv = sxv [buf][t][dg];
      float Bv = sB  [buf][t][n];
      float Cv = sC  [buf][t][n];
      float dA = __expf(dv * a);
      float dBu = dv * xv * Bv;
      hs = fmaf(dA, hs, dBu);
      float pred = fmaf(dA, hh, dBu);
      hh = fmaf(ALPHA_, hs - pred, pred);
      float contrib = hh * Cv;
      contrib += __shfl_xor(contrib, 1, 16);
      contrib += __shfl_xor(contrib, 2, 16);
      contrib += __shfl_xor(contrib, 4, 16);
      contrib += __shfl_xor(contrib, 8, 16);
      if (n == 0){
        float zv = sz[buf][t][dg];
        y2[(size_t)(mbase+t)*DI_ + d] = (contrib + dpv*xv) * (zv * sigmoidf_(zv));
      }
    }
    if (ch < L_/TC-1) WRITE(buf^1);
    __syncthreads();
    buf ^= 1;
  }
}

// ---------------- masked pooling (partial over t-chunks) ----------------
__global__ void k_pool(const float* __restrict__ h, const int* __restrict__ mask,
                       float* __restrict__ partial, float* __restrict__ pcnt){
  int p = blockIdx.x, b = blockIdx.y, d = threadIdx.x;
  float s = 0.f;
  for (int t=p*128; t<(p+1)*128; ++t){
    float mv = (float)mask[b*L_ + t];
    s = fmaf(mv, h[(size_t)(b*L_ + t)*DM + d], s);
  }
  partial[(size_t)(b*8+p)*DM + d] = s;
  if (d == 0){
    int c = 0;
    for (int t=p*128; t<(p+1)*128; ++t) c += mask[b*L_ + t];
    pcnt[b*8+p] = (float)c;
  }
}

// ---------------- final LN + classifier ----------------
__global__ void k_head(const float* __restrict__ partial, const float* __restrict__ pcnt,
                       const float* __restrict__ nw, const float* __restrict__ nb,
                       const float* __restrict__ cw, const float* __restrict__ cb,
                       float* __restrict__ out){
  int b = blockIdx.x, d = threadIdx.x;
  float s = 0.f;
  #pragma unroll
  for (int p=0;p<8;p++) s += partial[(size_t)(b*8+p)*DM + d];
  float cnt = 0.f;
  #pragma unroll
  for (int p=0;p<8;p++) cnt += pcnt[b*8+p];
  float v = s / cnt;
  float s1 = v, s2 = v*v;
  #pragma unroll
  for (int o=32;o>0;o>>=1){ s1 += __shfl_down(s1,o); s2 += __shfl_down(s2,o); }
  __shared__ float a1[4], a2[4];
  __shared__ float mv[2];
  int wid = d>>6, lane = d&63;
  if (lane==0){ a1[wid]=s1; a2[wid]=s2; }
  __syncthreads();
  if (d==0){
    float t1=a1[0]+a1[1]+a1[2]+a1[3];
    float t2=a2[0]+a2[1]+a2[2]+a2[3];
    float m = t1/(float)DM;
    float var = t2/(float)DM - m*m;
    mv[0]=m; mv[1]=rsqrtf(var+1e-5f);
  }
  __syncthreads();
  __shared__ float sp[DM];
  sp[d] = (v - mv[0])*mv[1]*nw[d] + nb[d];
  __syncthreads();
  __shared__ float cpart[NC_][16];
  if (d < NC_*16){
    int c = d >> 4, q = d & 15;
    float acc = 0.f;
    #pragma unroll
    for (int k=0;k<16;k++) acc = fmaf(sp[q*16+k], cw[(size_t)c*DM + q*16+k], acc);
    cpart[c][q] = acc;
  }
  __syncthreads();
  if (d < NC_){
    float acc = cb[d];
    #pragma unroll
    for (int q=0;q<16;q++) acc += cpart[d][q];
    out[b*NC_ + d] = acc;
  }
}

extern "C" void kernel_launch(void* const* d_in, const int* in_sizes, int n_in,
                              void* d_out, int out_size, void* d_ws, size_t ws_size,
                              hipStream_t stream){
  const float* emb   = (const float*)d_in[0];
  const float* pos   = (const float*)d_in[1];
  const float* ln_w  = (const float*)d_in[2];
  const float* ln_b  = (const float*)d_in[3];
  const float* ipw   = (const float*)d_in[4];
  const float* cw    = (const float*)d_in[5];
  const float* cb    = (const float*)d_in[6];
  const float* xpw   = (const float*)d_in[7];
  const float* dtw   = (const float*)d_in[8];
  const float* dtb   = (const float*)d_in[9];
  const float* A_log = (const float*)d_in[10];
  const float* Dp    = (const float*)d_in[11];
  const float* opw   = (const float*)d_in[12];
  const float* nw    = (const float*)d_in[13];
  const float* nb    = (const float*)d_in[14];
  const float* clw   = (const float*)d_in[15];
  const float* clb   = (const float*)d_in[16];
  const int*   ids   = (const int*)d_in[17];
  const int*   mask  = (const int*)d_in[18];
  float* out = (float*)d_out;

  float* ws   = (float*)d_ws;
  float* h    = ws;               // 2048*256
  float* hn   = h    + 524288;    // 2048*256
  float* xz   = hn   + 524288;    // 2048*1024
  float* xc   = xz   + 2097152;   // 2048*512
  float* xdbl = xc   + 1048576;   // 2048*48
  float* delta= xdbl + 98304;     // 2048*512
  float* y2   = delta+ 1048576;   // 2048*512
  float* part = y2   + 1048576;   // 2*8*256
  float* pcnt = part + 4096;      // 16

  k_embed<<<dim3(B_*L_), dim3(DM), 0, stream>>>(emb, pos, ids, h);
  for (int l=0; l<NL_; ++l){
    k_ln<<<dim3(B_*L_), dim3(DM), 0, stream>>>(h, hn, ln_w + l*DM, ln_b + l*DM);
    k_gemm<false><<<dim3((2*DI_)/64, (B_*L_)/64), 256, 0, stream>>>(
        hn, ipw + (size_t)l*2*DI_*DM, nullptr, xz, B_*L_, 2*DI_, DM);
    k_conv<<<dim3((B_*L_*DI_)/256), 256, 0, stream>>>(xz, cw + l*DI_*DC_, cb + l*DI_, xc);
    k_xproj_dt<<<dim3(B_*L_), 256, 0, stream>>>(
        xc, xpw + (size_t)l*48*DI_, dtw + (size_t)l*DI_*16, dtb + l*DI_, xdbl, delta);
    k_scan<<<dim3(64), 256, 0, stream>>>(
        delta, xc, xdbl, xz, A_log + (size_t)l*DI_*DS_, Dp + l*DI_, y2);
    k_gemm<true><<<dim3(DM/64, (B_*L_)/64), 256, 0, stream>>>(
        y2, opw + (size_t)l*DM*DI_, h, h, B_*L_, DM, DI_);
  }
  k_pool<<<dim3(8, B_), DM, 0, stream>>>(h, mask, part, pcnt);
  k_head<<<dim3(B_), DM, 0, stream>>>(part, pcnt, nw, nb, clw, clb, out);
}

// Round 2
// 847.374 us; speedup vs baseline: 2.4719x; 2.4719x over previous
//
#include <hip/hip_runtime.h>
#include <math.h>

#define B_ 2
#define L_ 1024
#define DM 256
#define NL_ 6
#define DI_ 512
#define DS_ 16
#define DC_ 4
#define NC_ 10
#define ALPHA_ 0.1f
#define LC 16
#define NCH (L_/LC)          // 64 chunks
#define NCHAIN (B_*DI_*DS_)  // 16384 chains
// beta = 1-ALPHA; beta^LC
#define BETA_LC 0.1853020188851841f

__device__ __forceinline__ float sigmoidf_(float x){ return 1.f/(1.f+__expf(-x)); }

// ---------------- embed: h = emb[x] + pos_emb[:L] ----------------
__global__ void k_embed(const float* __restrict__ emb, const float* __restrict__ pos,
                        const int* __restrict__ ids, float* __restrict__ h){
  int row = blockIdx.x;            // 0..B*L-1
  int t = row & (L_-1);
  int d = threadIdx.x;             // 0..255
  int v = ids[row];
  h[(size_t)row*DM + d] = emb[(size_t)v*DM + d] + pos[(size_t)t*DM + d];
}

// ---------------- layernorm over rows of 256 ----------------
__global__ void k_ln(const float* __restrict__ x, float* __restrict__ y,
                     const float* __restrict__ w, const float* __restrict__ b){
  int row = blockIdx.x;
  int d = threadIdx.x;
  float v = x[(size_t)row*DM + d];
  float s1 = v, s2 = v*v;
  #pragma unroll
  for (int o=32;o>0;o>>=1){ s1 += __shfl_down(s1,o); s2 += __shfl_down(s2,o); }
  __shared__ float a1[4], a2[4];
  __shared__ float mv[2];
  int wid = d>>6, lane = d&63;
  if (lane==0){ a1[wid]=s1; a2[wid]=s2; }
  __syncthreads();
  if (d==0){
    float t1=a1[0]+a1[1]+a1[2]+a1[3];
    float t2=a2[0]+a2[1]+a2[2]+a2[3];
    float m = t1/(float)DM;
    float var = t2/(float)DM - m*m;
    mv[0]=m; mv[1]=rsqrtf(var+1e-5f);
  }
  __syncthreads();
  y[(size_t)row*DM+d] = (v - mv[0])*mv[1]*w[d] + b[d];
}

// ---------------- C[M,N] = A[M,K] @ W[N,K]^T (+RES) ----------------
template<bool ADD_RES>
__global__ void k_gemm(const float* __restrict__ A, const float* __restrict__ W,
                       const float* __restrict__ RES, float* __restrict__ C,
                       int M, int N, int K){
  const int BM=64, BN=64, BK=16;
  __shared__ float As[BK][BM];
  __shared__ float Ws[BK][BN];
  int bm = blockIdx.y*BM, bn = blockIdx.x*BN;
  int tid = threadIdx.x;           // 256
  int tx = tid & 15, ty = tid >> 4;
  int lr = tid >> 2, lc4 = (tid & 3) << 2;
  float acc[4][4] = {};
  for (int k0=0;k0<K;k0+=BK){
    float4 av = *reinterpret_cast<const float4*>(&A[(size_t)(bm+lr)*K + k0 + lc4]);
    float4 wv = *reinterpret_cast<const float4*>(&W[(size_t)(bn+lr)*K + k0 + lc4]);
    As[lc4+0][lr]=av.x; As[lc4+1][lr]=av.y; As[lc4+2][lr]=av.z; As[lc4+3][lr]=av.w;
    Ws[lc4+0][lr]=wv.x; Ws[lc4+1][lr]=wv.y; Ws[lc4+2][lr]=wv.z; Ws[lc4+3][lr]=wv.w;
    __syncthreads();
    #pragma unroll
    for (int k=0;k<BK;k++){
      float4 a4 = *reinterpret_cast<const float4*>(&As[k][ty*4]);
      float4 b4 = *reinterpret_cast<const float4*>(&Ws[k][tx*4]);
      float a[4]={a4.x,a4.y,a4.z,a4.w}, bb[4]={b4.x,b4.y,b4.z,b4.w};
      #pragma unroll
      for (int i=0;i<4;i++)
        #pragma unroll
        for (int j=0;j<4;j++)
          acc[i][j] = fmaf(a[i], bb[j], acc[i][j]);
    }
    __syncthreads();
  }
  #pragma unroll
  for (int i=0;i<4;i++){
    int r = bm + ty*4 + i;
    #pragma unroll
    for (int j=0;j<4;j++){
      int c = bn + tx*4 + j;
      float v = acc[i][j];
      if (ADD_RES) v += RES[(size_t)r*N + c];
      C[(size_t)r*N + c] = v;
    }
  }
}

// ---------------- causal depthwise conv (DC=4) + SiLU ----------------
__global__ void k_conv(const float* __restrict__ xz, const float* __restrict__ cw,
                       const float* __restrict__ cb, float* __restrict__ xc){
  int gid = blockIdx.x*blockDim.x + threadIdx.x; // B*L*DI
  int d = gid & (DI_-1);
  int m = gid >> 9;
  int t = m & (L_-1);
  float acc = cb[d];
  #pragma unroll
  for (int k=0;k<DC_;k++){
    int tt = t - 3 + k;
    if (tt >= 0)
      acc = fmaf(cw[d*DC_+k], xz[(size_t)(m-3+k)*(2*DI_) + d], acc);
  }
  xc[gid] = acc * sigmoidf_(acc);
}

// ---------------- x_proj (48x512) + dt_proj (512x16) + softplus ----------------
__global__ void k_xproj_dt(const float* __restrict__ xc, const float* __restrict__ xw,
                           const float* __restrict__ dtw, const float* __restrict__ dtb,
                           float* __restrict__ xdbl, float* __restrict__ delta){
  int m = blockIdx.x;
  int tid = threadIdx.x;
  __shared__ float sx[DI_];
  __shared__ float sp[48][4];
  __shared__ float sd[16];
  if (tid < 128)
    *reinterpret_cast<float4*>(&sx[tid*4]) =
      *reinterpret_cast<const float4*>(&xc[(size_t)m*DI_ + tid*4]);
  __syncthreads();
  if (tid < 192){
    int o = tid >> 2, p = tid & 3;
    const float* w = &xw[(size_t)o*DI_ + p*128];
    const float* xs = &sx[p*128];
    float acc = 0.f;
    #pragma unroll 8
    for (int k=0;k<128;k++) acc = fmaf(xs[k], w[k], acc);
    sp[o][p] = acc;
  }
  __syncthreads();
  if (tid < 48){
    float v = sp[tid][0]+sp[tid][1]+sp[tid][2]+sp[tid][3];
    xdbl[(size_t)m*48 + tid] = v;
    if (tid < 16) sd[tid] = v;
  }
  __syncthreads();
  for (int n=tid; n<DI_; n+=256){
    float acc = dtb[n];
    #pragma unroll
    for (int k=0;k<16;k++) acc = fmaf(sd[k], dtw[n*16+k], acc);
    delta[(size_t)m*DI_ + n] = (acc > 20.f) ? acc : log1pf(__expf(acc));
  }
}

// ================= chunked parallel scan =================
// Pass A: per-chunk local scan summary (zero init): cp = prod(dA), hs_loc, hh_loc
__global__ void k_scanA(const float* __restrict__ delta, const float* __restrict__ xc,
                        const float* __restrict__ xdbl, const float* __restrict__ A_log,
                        float* __restrict__ cpArr, float* __restrict__ slocArr,
                        float* __restrict__ hlocArr){
  int j = blockIdx.x, g = blockIdx.y, b = blockIdx.z;
  int tid = threadIdx.x;                 // 256 = 16 dg x 16 n
  int n = tid & 15, dg = tid >> 4;
  int d0 = g*16;
  __shared__ float sdel[LC][16], sxv[LC][16], sB[LC][16];
  {
    int t = tid >> 4, c2 = tid & 15;
    int m = b*L_ + j*LC + t;
    sdel[t][c2] = delta[(size_t)m*DI_ + d0 + c2];
    sxv[t][c2]  = xc  [(size_t)m*DI_ + d0 + c2];
    sB[t][c2]   = xdbl[(size_t)m*48 + 16 + c2];
  }
  __syncthreads();
  int d = d0 + dg;
  float a = -__expf(A_log[d*DS_ + n]);
  float dA[LC], dBu[LC];
  #pragma unroll
  for (int t=0;t<LC;t++){
    float dv = sdel[t][dg];
    dA[t]  = __expf(dv * a);
    dBu[t] = dv * sxv[t][dg] * sB[t][n];
  }
  float hs=0.f, hh=0.f, cp=1.f;
  #pragma unroll
  for (int t=0;t<LC;t++){
    float mix = fmaf(ALPHA_, hs - hh, hh);
    hs = fmaf(dA[t], hs, dBu[t]);
    hh = fmaf(dA[t], mix, dBu[t]);
    cp *= dA[t];
  }
  size_t o = (size_t)j*NCHAIN + (b*DI_ + d0)*DS_ + tid;
  cpArr[o]=cp; slocArr[o]=hs; hlocArr[o]=hh;
}

// Pass B: sequential combine over chunks per chain; emits per-chunk init states
__global__ void k_scanB(const float* __restrict__ cpArr, const float* __restrict__ slocArr,
                        const float* __restrict__ hlocArr,
                        float* __restrict__ s0Arr, float* __restrict__ h0Arr){
  int c = blockIdx.x*256 + threadIdx.x;  // 0..NCHAIN-1
  float s=0.f, h=0.f;
  #pragma unroll
  for (int j=0;j<NCH;j++){
    size_t o = (size_t)j*NCHAIN + c;
    s0Arr[o]=s; h0Arr[o]=h;
    float cp = cpArr[o], sl = slocArr[o], hl = hlocArr[o];
    // hh_end = cp*( (1-b^L)*s0 + b^L*h0 ) + hh_loc ; hs_end = cp*s0 + hs_loc
    float snew = fmaf(cp, s, sl);
    h = fmaf(cp, fmaf(BETA_LC, h - s, s), hl);
    s = snew;
  }
}

// Pass C: re-run chunk with known init, produce gated y2
__global__ void k_scanC(const float* __restrict__ delta, const float* __restrict__ xc,
                        const float* __restrict__ xdbl, const float* __restrict__ xz,
                        const float* __restrict__ A_log, const float* __restrict__ Dp,
                        const float* __restrict__ s0Arr, const float* __restrict__ h0Arr,
                        float* __restrict__ y2){
  int j = blockIdx.x, g = blockIdx.y, b = blockIdx.z;
  int tid = threadIdx.x;
  int n = tid & 15, dg = tid >> 4;
  int d0 = g*16;
  __shared__ float sdel[LC][16], sxv[LC][16], sB[LC][16], sC[LC][16], sz[LC][16], sy[LC][16];
  {
    int t = tid >> 4, c2 = tid & 15;
    int m = b*L_ + j*LC + t;
    sdel[t][c2] = delta[(size_t)m*DI_ + d0 + c2];
    sxv[t][c2]  = xc  [(size_t)m*DI_ + d0 + c2];
    sB[t][c2]   = xdbl[(size_t)m*48 + 16 + c2];
    sC[t][c2]   = xdbl[(size_t)m*48 + 32 + c2];
    sz[t][c2]   = xz  [(size_t)m*(2*DI_) + DI_ + d0 + c2];
  }
  __syncthreads();
  int d = d0 + dg;
  float a = -__expf(A_log[d*DS_ + n]);
  float dA[LC], dBu[LC], ct[LC];
  #pragma unroll
  for (int t=0;t<LC;t++){
    float dv = sdel[t][dg];
    dA[t]  = __expf(dv * a);
    dBu[t] = dv * sxv[t][dg] * sB[t][n];
    ct[t]  = sC[t][n];
  }
  size_t o = (size_t)j*NCHAIN + (b*DI_ + d0)*DS_ + tid;
  float hs = s0Arr[o], hh = h0Arr[o];
  float yv[LC];
  #pragma unroll
  for (int t=0;t<LC;t++){
    float mix = fmaf(ALPHA_, hs - hh, hh);
    hs = fmaf(dA[t], hs, dBu[t]);
    hh = fmaf(dA[t], mix, dBu[t]);
    yv[t] = hh * ct[t];
  }
  // independent butterfly reductions over n (all within a wave: n = tid&15)
  #pragma unroll
  for (int t=0;t<LC;t++){
    yv[t] += __shfl_xor(yv[t], 1, 16);
    yv[t] += __shfl_xor(yv[t], 2, 16);
    yv[t] += __shfl_xor(yv[t], 4, 16);
    yv[t] += __shfl_xor(yv[t], 8, 16);
  }
  if (n == 0){
    #pragma unroll
    for (int t=0;t<LC;t++) sy[t][dg] = yv[t];
  }
  __syncthreads();
  // gated store, coalesced: thread (t2, dd)
  {
    int t2 = tid >> 4, dd = tid & 15;
    float xvv = sxv[t2][dd];
    float zv  = sz [t2][dd];
    float yfin = (sy[t2][dd] + Dp[d0+dd]*xvv) * (zv * sigmoidf_(zv));
    y2[(size_t)(b*L_ + j*LC + t2)*DI_ + d0 + dd] = yfin;
  }
}

// ---------------- masked pooling (partial over t-chunks) ----------------
__global__ void k_pool(const float* __restrict__ h, const int* __restrict__ mask,
                       float* __restrict__ partial, float* __restrict__ pcnt){
  int p = blockIdx.x, b = blockIdx.y, d = threadIdx.x;
  float s = 0.f;
  for (int t=p*128; t<(p+1)*128; ++t){
    float mv = (float)mask[b*L_ + t];
    s = fmaf(mv, h[(size_t)(b*L_ + t)*DM + d], s);
  }
  partial[(size_t)(b*8+p)*DM + d] = s;
  if (d == 0){
    int c = 0;
    for (int t=p*128; t<(p+1)*128; ++t) c += mask[b*L_ + t];
    pcnt[b*8+p] = (float)c;
  }
}

// ---------------- final LN + classifier ----------------
__global__ void k_head(const float* __restrict__ partial, const float* __restrict__ pcnt,
                       const float* __restrict__ nw, const float* __restrict__ nb,
                       const float* __restrict__ cw, const float* __restrict__ cb,
                       float* __restrict__ out){
  int b = blockIdx.x, d = threadIdx.x;
  float s = 0.f;
  #pragma unroll
  for (int p=0;p<8;p++) s += partial[(size_t)(b*8+p)*DM + d];
  float cnt = 0.f;
  #pragma unroll
  for (int p=0;p<8;p++) cnt += pcnt[b*8+p];
  float v = s / cnt;
  float s1 = v, s2 = v*v;
  #pragma unroll
  for (int o=32;o>0;o>>=1){ s1 += __shfl_down(s1,o); s2 += __shfl_down(s2,o); }
  __shared__ float a1[4], a2[4];
  __shared__ float mv[2];
  int wid = d>>6, lane = d&63;
  if (lane==0){ a1[wid]=s1; a2[wid]=s2; }
  __syncthreads();
  if (d==0){
    float t1=a1[0]+a1[1]+a1[2]+a1[3];
    float t2=a2[0]+a2[1]+a2[2]+a2[3];
    float m = t1/(float)DM;
    float var = t2/(float)DM - m*m;
    mv[0]=m; mv[1]=rsqrtf(var+1e-5f);
  }
  __syncthreads();
  __shared__ float sp[DM];
  sp[d] = (v - mv[0])*mv[1]*nw[d] + nb[d];
  __syncthreads();
  __shared__ float cpart[NC_][16];
  if (d < NC_*16){
    int c = d >> 4, q = d & 15;
    float acc = 0.f;
    #pragma unroll
    for (int k=0;k<16;k++) acc = fmaf(sp[q*16+k], cw[(size_t)c*DM + q*16+k], acc);
    cpart[c][q] = acc;
  }
  __syncthreads();
  if (d < NC_){
    float acc = cb[d];
    #pragma unroll
    for (int q=0;q<16;q++) acc += cpart[d][q];
    out[b*NC_ + d] = acc;
  }
}

extern "C" void kernel_launch(void* const* d_in, const int* in_sizes, int n_in,
                              void* d_out, int out_size, void* d_ws, size_t ws_size,
                              hipStream_t stream){
  const float* emb   = (const float*)d_in[0];
  const float* pos   = (const float*)d_in[1];
  const float* ln_w  = (const float*)d_in[2];
  const float* ln_b  = (const float*)d_in[3];
  const float* ipw   = (const float*)d_in[4];
  const float* cw    = (const float*)d_in[5];
  const float* cb    = (const float*)d_in[6];
  const float* xpw   = (const float*)d_in[7];
  const float* dtw   = (const float*)d_in[8];
  const float* dtb   = (const float*)d_in[9];
  const float* A_log = (const float*)d_in[10];
  const float* Dp    = (const float*)d_in[11];
  const float* opw   = (const float*)d_in[12];
  const float* nw    = (const float*)d_in[13];
  const float* nb    = (const float*)d_in[14];
  const float* clw   = (const float*)d_in[15];
  const float* clb   = (const float*)d_in[16];
  const int*   ids   = (const int*)d_in[17];
  const int*   mask  = (const int*)d_in[18];
  float* out = (float*)d_out;

  float* ws   = (float*)d_ws;
  float* h    = ws;               // 2048*256
  float* hn   = h    + 524288;    // 2048*256
  float* xz   = hn   + 524288;    // 2048*1024
  float* xc   = xz   + 2097152;   // 2048*512
  float* xdbl = xc   + 1048576;   // 2048*48
  float* delta= xdbl + 98304;     // 2048*512
  float* y2   = delta+ 1048576;   // 2048*512
  float* part = y2   + 1048576;   // 2*8*256
  float* pcnt = part + 4096;      // 16
  float* cpA  = pcnt + 16;        // NCH*NCHAIN = 1048576
  float* slocA= cpA  + 1048576;
  float* hlocA= slocA+ 1048576;
  float* s0A  = hlocA+ 1048576;
  float* h0A  = s0A  + 1048576;

  k_embed<<<dim3(B_*L_), dim3(DM), 0, stream>>>(emb, pos, ids, h);
  for (int l=0; l<NL_; ++l){
    k_ln<<<dim3(B_*L_), dim3(DM), 0, stream>>>(h, hn, ln_w + l*DM, ln_b + l*DM);
    k_gemm<false><<<dim3((2*DI_)/64, (B_*L_)/64), 256, 0, stream>>>(
        hn, ipw + (size_t)l*2*DI_*DM, nullptr, xz, B_*L_, 2*DI_, DM);
    k_conv<<<dim3((B_*L_*DI_)/256), 256, 0, stream>>>(xz, cw + l*DI_*DC_, cb + l*DI_, xc);
    k_xproj_dt<<<dim3(B_*L_), 256, 0, stream>>>(
        xc, xpw + (size_t)l*48*DI_, dtw + (size_t)l*DI_*16, dtb + l*DI_, xdbl, delta);
    k_scanA<<<dim3(NCH, DI_/16, B_), 256, 0, stream>>>(
        delta, xc, xdbl, A_log + (size_t)l*DI_*DS_, cpA, slocA, hlocA);
    k_scanB<<<dim3(NCHAIN/256), 256, 0, stream>>>(cpA, slocA, hlocA, s0A, h0A);
    k_scanC<<<dim3(NCH, DI_/16, B_), 256, 0, stream>>>(
        delta, xc, xdbl, xz, A_log + (size_t)l*DI_*DS_, Dp + l*DI_, s0A, h0A, y2);
    k_gemm<true><<<dim3(DM/64, (B_*L_)/64), 256, 0, stream>>>(
        y2, opw + (size_t)l*DM*DI_, h, h, B_*L_, DM, DI_);
  }
  k_pool<<<dim3(8, B_), DM, 0, stream>>>(h, mask, part, pcnt);
  k_head<<<dim3(B_), DM, 0, stream>>>(part, pcnt, nw, nb, clw, clb, out);
}

// Round 3
// 671.864 us; speedup vs baseline: 3.1177x; 1.2612x over previous
//
#include <hip/hip_runtime.h>
#include <math.h>

#define B_ 2
#define L_ 1024
#define DM 256
#define NL_ 6
#define DI_ 512
#define DS_ 16
#define DC_ 4
#define NC_ 10
#define ALPHA_ 0.1f
#define LC 16
#define NCH (L_/LC)          // 64 chunks
#define NCHAIN (B_*DI_*DS_)  // 16384 chains
#define BETA_LC 0.1853020188851841f   // (1-ALPHA)^LC

typedef unsigned short ushort_t;
typedef __attribute__((ext_vector_type(8))) short s16x8;      // 8 bf16 (MFMA A/B frag)
typedef __attribute__((ext_vector_type(4))) float f32x4;      // MFMA C/D frag
typedef __attribute__((ext_vector_type(8))) unsigned short u16x8;

__device__ __forceinline__ float sigmoidf_(float x){ return 1.f/(1.f+__expf(-x)); }

__device__ __forceinline__ ushort_t f2bf(float f){
  union{float f;unsigned u;} c; c.f = f;
  unsigned u = c.u;
  return (ushort_t)((u + 0x7fffu + ((u>>16)&1u)) >> 16);
}

// ---------------- embed ----------------
__global__ void k_embed(const float* __restrict__ emb, const float* __restrict__ pos,
                        const int* __restrict__ ids, float* __restrict__ h){
  int row = blockIdx.x;
  int t = row & (L_-1);
  int d = threadIdx.x;
  int v = ids[row];
  h[(size_t)row*DM + d] = emb[(size_t)v*DM + d] + pos[(size_t)t*DM + d];
}

// ---------------- fp32 -> bf16 weight conversion ----------------
__global__ void k_cvt(const float* __restrict__ in, ushort_t* __restrict__ o, int n){
  int i = (blockIdx.x*256 + threadIdx.x)*4;
  if (i < n){
    float4 v = *reinterpret_cast<const float4*>(&in[i]);
    ushort4 r;
    r.x = f2bf(v.x); r.y = f2bf(v.y); r.z = f2bf(v.z); r.w = f2bf(v.w);
    *reinterpret_cast<ushort4*>(&o[i]) = r;
  }
}

// ---------------- layernorm -> bf16 output ----------------
__global__ void k_ln(const float* __restrict__ x, ushort_t* __restrict__ y,
                     const float* __restrict__ w, const float* __restrict__ b){
  int row = blockIdx.x;
  int d = threadIdx.x;
  float v = x[(size_t)row*DM + d];
  float s1 = v, s2 = v*v;
  #pragma unroll
  for (int o=32;o>0;o>>=1){ s1 += __shfl_down(s1,o); s2 += __shfl_down(s2,o); }
  __shared__ float a1[4], a2[4];
  __shared__ float mv[2];
  int wid = d>>6, lane = d&63;
  if (lane==0){ a1[wid]=s1; a2[wid]=s2; }
  __syncthreads();
  if (d==0){
    float t1=a1[0]+a1[1]+a1[2]+a1[3];
    float t2=a2[0]+a2[1]+a2[2]+a2[3];
    float m = t1/(float)DM;
    float var = t2/(float)DM - m*m;
    mv[0]=m; mv[1]=rsqrtf(var+1e-5f);
  }
  __syncthreads();
  y[(size_t)row*DM+d] = f2bf((v - mv[0])*mv[1]*w[d] + b[d]);
}

// ---------------- bf16 MFMA GEMM: C[M,N] = A[M,K] @ W[N,K]^T (+RES), fp32 out ----------------
// 64x64 tile, 4 waves (2x2), BK=32, one 16x16x32 mfma quad per wave per k-step.
template<bool ADD_RES>
__global__ __launch_bounds__(256) void k_gemm_bf(const ushort_t* __restrict__ A,
                       const ushort_t* __restrict__ W, const float* __restrict__ RES,
                       float* __restrict__ C, int M, int N, int K){
  __shared__ ushort_t As[64][40];   // +8 pad: row stride 20 words -> 2-way bank alias (free)
  __shared__ ushort_t Ws[64][40];
  int bm = blockIdx.y<<6, bn = blockIdx.x<<6;
  int tid = threadIdx.x;
  int lane = tid & 63, wid = tid >> 6;
  int wm = (wid>>1)<<5, wn = (wid&1)<<5;        // wave's 32x32 quadrant
  int fr = lane & 15, fk = (lane>>4)<<3;        // fragment row, k-offset (8 elems)
  int sr = tid>>2, sc = (tid&3)<<3;             // staging: row, 8-elem chunk
  const ushort_t* pa = &A[(size_t)(bm+sr)*K + sc];
  const ushort_t* pw = &W[(size_t)(bn+sr)*K + sc];
  f32x4 acc[2][2] = {};
  for (int k0=0;k0<K;k0+=32){
    u16x8 av = *reinterpret_cast<const u16x8*>(pa + k0);
    u16x8 wv = *reinterpret_cast<const u16x8*>(pw + k0);
    *reinterpret_cast<u16x8*>(&As[sr][sc]) = av;
    *reinterpret_cast<u16x8*>(&Ws[sr][sc]) = wv;
    __syncthreads();
    s16x8 a0 = *reinterpret_cast<const s16x8*>(&As[wm + fr][fk]);
    s16x8 a1 = *reinterpret_cast<const s16x8*>(&As[wm + 16 + fr][fk]);
    s16x8 b0 = *reinterpret_cast<const s16x8*>(&Ws[wn + fr][fk]);
    s16x8 b1 = *reinterpret_cast<const s16x8*>(&Ws[wn + 16 + fr][fk]);
    acc[0][0] = __builtin_amdgcn_mfma_f32_16x16x32_bf16(a0, b0, acc[0][0], 0, 0, 0);
    acc[0][1] = __builtin_amdgcn_mfma_f32_16x16x32_bf16(a0, b1, acc[0][1], 0, 0, 0);
    acc[1][0] = __builtin_amdgcn_mfma_f32_16x16x32_bf16(a1, b0, acc[1][0], 0, 0, 0);
    acc[1][1] = __builtin_amdgcn_mfma_f32_16x16x32_bf16(a1, b1, acc[1][1], 0, 0, 0);
    __syncthreads();
  }
  int cr = (lane>>4)<<2, cc = lane & 15;
  #pragma unroll
  for (int i=0;i<2;i++){
    #pragma unroll
    for (int j=0;j<2;j++){
      int row = bm + wm + (i<<4) + cr;
      int col = bn + wn + (j<<4) + cc;
      #pragma unroll
      for (int r=0;r<4;r++){
        float v = acc[i][j][r];
        if (ADD_RES) v += RES[(size_t)(row+r)*N + col];
        C[(size_t)(row+r)*N + col] = v;
      }
    }
  }
}

// ---------------- causal depthwise conv (DC=4) + SiLU ----------------
__global__ void k_conv(const float* __restrict__ xz, const float* __restrict__ cw,
                       const float* __restrict__ cb, float* __restrict__ xc){
  int gid = blockIdx.x*blockDim.x + threadIdx.x; // B*L*DI
  int d = gid & (DI_-1);
  int m = gid >> 9;
  int t = m & (L_-1);
  float acc = cb[d];
  #pragma unroll
  for (int k=0;k<DC_;k++){
    int tt = t - 3 + k;
    if (tt >= 0)
      acc = fmaf(cw[d*DC_+k], xz[(size_t)(m-3+k)*(2*DI_) + d], acc);
  }
  xc[gid] = acc * sigmoidf_(acc);
}

// ---------------- x_proj (48x512) + dt_proj (512x16) + softplus ----------------
__global__ void k_xproj_dt(const float* __restrict__ xc, const float* __restrict__ xw,
                           const float* __restrict__ dtw, const float* __restrict__ dtb,
                           float* __restrict__ xdbl, float* __restrict__ delta){
  int m = blockIdx.x;
  int tid = threadIdx.x;
  __shared__ float sx[DI_];
  __shared__ float sp[48][4];
  __shared__ float sd[16];
  if (tid < 128)
    *reinterpret_cast<float4*>(&sx[tid*4]) =
      *reinterpret_cast<const float4*>(&xc[(size_t)m*DI_ + tid*4]);
  __syncthreads();
  if (tid < 192){
    int o = tid >> 2, p = tid & 3;
    const float* w = &xw[(size_t)o*DI_ + p*128];
    const float* xs = &sx[p*128];
    float acc = 0.f;
    #pragma unroll 8
    for (int k=0;k<128;k++) acc = fmaf(xs[k], w[k], acc);
    sp[o][p] = acc;
  }
  __syncthreads();
  if (tid < 48){
    float v = sp[tid][0]+sp[tid][1]+sp[tid][2]+sp[tid][3];
    xdbl[(size_t)m*48 + tid] = v;
    if (tid < 16) sd[tid] = v;
  }
  __syncthreads();
  for (int n=tid; n<DI_; n+=256){
    float acc = dtb[n];
    #pragma unroll
    for (int k=0;k<16;k++) acc = fmaf(sd[k], dtw[n*16+k], acc);
    delta[(size_t)m*DI_ + n] = (acc > 20.f) ? acc : log1pf(__expf(acc));
  }
}

// ================= chunked parallel scan =================
__global__ void k_scanA(const float* __restrict__ delta, const float* __restrict__ xc,
                        const float* __restrict__ xdbl, const float* __restrict__ A_log,
                        float* __restrict__ cpArr, float* __restrict__ slocArr,
                        float* __restrict__ hlocArr){
  int j = blockIdx.x, g = blockIdx.y, b = blockIdx.z;
  int tid = threadIdx.x;
  int n = tid & 15, dg = tid >> 4;
  int d0 = g*16;
  __shared__ float sdel[LC][16], sxv[LC][16], sB[LC][16];
  {
    int t = tid >> 4, c2 = tid & 15;
    int m = b*L_ + j*LC + t;
    sdel[t][c2] = delta[(size_t)m*DI_ + d0 + c2];
    sxv[t][c2]  = xc  [(size_t)m*DI_ + d0 + c2];
    sB[t][c2]   = xdbl[(size_t)m*48 + 16 + c2];
  }
  __syncthreads();
  int d = d0 + dg;
  float a = -__expf(A_log[d*DS_ + n]);
  float dA[LC], dBu[LC];
  #pragma unroll
  for (int t=0;t<LC;t++){
    float dv = sdel[t][dg];
    dA[t]  = __expf(dv * a);
    dBu[t] = dv * sxv[t][dg] * sB[t][n];
  }
  float hs=0.f, hh=0.f, cp=1.f;
  #pragma unroll
  for (int t=0;t<LC;t++){
    float mix = fmaf(ALPHA_, hs - hh, hh);
    hs = fmaf(dA[t], hs, dBu[t]);
    hh = fmaf(dA[t], mix, dBu[t]);
    cp *= dA[t];
  }
  size_t o = (size_t)j*NCHAIN + (b*DI_ + d0)*DS_ + tid;
  cpArr[o]=cp; slocArr[o]=hs; hlocArr[o]=hh;
}

__global__ void k_scanB(const float* __restrict__ cpArr, const float* __restrict__ slocArr,
                        const float* __restrict__ hlocArr,
                        float* __restrict__ s0Arr, float* __restrict__ h0Arr){
  int c = blockIdx.x*256 + threadIdx.x;
  float s=0.f, h=0.f;
  #pragma unroll
  for (int j=0;j<NCH;j++){
    size_t o = (size_t)j*NCHAIN + c;
    s0Arr[o]=s; h0Arr[o]=h;
    float cp = cpArr[o], sl = slocArr[o], hl = hlocArr[o];
    float snew = fmaf(cp, s, sl);
    h = fmaf(cp, fmaf(BETA_LC, h - s, s), hl);
    s = snew;
  }
}

// Pass C: re-run chunk with known init, produce gated y2 in bf16
__global__ void k_scanC(const float* __restrict__ delta, const float* __restrict__ xc,
                        const float* __restrict__ xdbl, const float* __restrict__ xz,
                        const float* __restrict__ A_log, const float* __restrict__ Dp,
                        const float* __restrict__ s0Arr, const float* __restrict__ h0Arr,
                        ushort_t* __restrict__ y2b){
  int j = blockIdx.x, g = blockIdx.y, b = blockIdx.z;
  int tid = threadIdx.x;
  int n = tid & 15, dg = tid >> 4;
  int d0 = g*16;
  __shared__ float sdel[LC][16], sxv[LC][16], sB[LC][16], sC[LC][16], sz[LC][16], sy[LC][16];
  {
    int t = tid >> 4, c2 = tid & 15;
    int m = b*L_ + j*LC + t;
    sdel[t][c2] = delta[(size_t)m*DI_ + d0 + c2];
    sxv[t][c2]  = xc  [(size_t)m*DI_ + d0 + c2];
    sB[t][c2]   = xdbl[(size_t)m*48 + 16 + c2];
    sC[t][c2]   = xdbl[(size_t)m*48 + 32 + c2];
    sz[t][c2]   = xz  [(size_t)m*(2*DI_) + DI_ + d0 + c2];
  }
  __syncthreads();
  int d = d0 + dg;
  float a = -__expf(A_log[d*DS_ + n]);
  float dA[LC], dBu[LC], ct[LC];
  #pragma unroll
  for (int t=0;t<LC;t++){
    float dv = sdel[t][dg];
    dA[t]  = __expf(dv * a);
    dBu[t] = dv * sxv[t][dg] * sB[t][n];
    ct[t]  = sC[t][n];
  }
  size_t o = (size_t)j*NCHAIN + (b*DI_ + d0)*DS_ + tid;
  float hs = s0Arr[o], hh = h0Arr[o];
  float yv[LC];
  #pragma unroll
  for (int t=0;t<LC;t++){
    float mix = fmaf(ALPHA_, hs - hh, hh);
    hs = fmaf(dA[t], hs, dBu[t]);
    hh = fmaf(dA[t], mix, dBu[t]);
    yv[t] = hh * ct[t];
  }
  #pragma unroll
  for (int t=0;t<LC;t++){
    yv[t] += __shfl_xor(yv[t], 1, 16);
    yv[t] += __shfl_xor(yv[t], 2, 16);
    yv[t] += __shfl_xor(yv[t], 4, 16);
    yv[t] += __shfl_xor(yv[t], 8, 16);
  }
  if (n == 0){
    #pragma unroll
    for (int t=0;t<LC;t++) sy[t][dg] = yv[t];
  }
  __syncthreads();
  {
    int t2 = tid >> 4, dd = tid & 15;
    float xvv = sxv[t2][dd];
    float zv  = sz [t2][dd];
    float yfin = (sy[t2][dd] + Dp[d0+dd]*xvv) * (zv * sigmoidf_(zv));
    y2b[(size_t)(b*L_ + j*LC + t2)*DI_ + d0 + dd] = f2bf(yfin);
  }
}

// ---------------- masked pooling ----------------
__global__ void k_pool(const float* __restrict__ h, const int* __restrict__ mask,
                       float* __restrict__ partial, float* __restrict__ pcnt){
  int p = blockIdx.x, b = blockIdx.y, d = threadIdx.x;
  float s = 0.f;
  for (int t=p*128; t<(p+1)*128; ++t){
    float mv = (float)mask[b*L_ + t];
    s = fmaf(mv, h[(size_t)(b*L_ + t)*DM + d], s);
  }
  partial[(size_t)(b*8+p)*DM + d] = s;
  if (d == 0){
    int c = 0;
    for (int t=p*128; t<(p+1)*128; ++t) c += mask[b*L_ + t];
    pcnt[b*8+p] = (float)c;
  }
}

// ---------------- final LN + classifier ----------------
__global__ void k_head(const float* __restrict__ partial, const float* __restrict__ pcnt,
                       const float* __restrict__ nw, const float* __restrict__ nb,
                       const float* __restrict__ cw, const float* __restrict__ cb,
                       float* __restrict__ out){
  int b = blockIdx.x, d = threadIdx.x;
  float s = 0.f;
  #pragma unroll
  for (int p=0;p<8;p++) s += partial[(size_t)(b*8+p)*DM + d];
  float cnt = 0.f;
  #pragma unroll
  for (int p=0;p<8;p++) cnt += pcnt[b*8+p];
  float v = s / cnt;
  float s1 = v, s2 = v*v;
  #pragma unroll
  for (int o=32;o>0;o>>=1){ s1 += __shfl_down(s1,o); s2 += __shfl_down(s2,o); }
  __shared__ float a1[4], a2[4];
  __shared__ float mv[2];
  int wid = d>>6, lane = d&63;
  if (lane==0){ a1[wid]=s1; a2[wid]=s2; }
  __syncthreads();
  if (d==0){
    float t1=a1[0]+a1[1]+a1[2]+a1[3];
    float t2=a2[0]+a2[1]+a2[2]+a2[3];
    float m = t1/(float)DM;
    float var = t2/(float)DM - m*m;
    mv[0]=m; mv[1]=rsqrtf(var+1e-5f);
  }
  __syncthreads();
  __shared__ float sp[DM];
  sp[d] = (v - mv[0])*mv[1]*nw[d] + nb[d];
  __syncthreads();
  __shared__ float cpart[NC_][16];
  if (d < NC_*16){
    int c = d >> 4, q = d & 15;
    float acc = 0.f;
    #pragma unroll
    for (int k=0;k<16;k++) acc = fmaf(sp[q*16+k], cw[(size_t)c*DM + q*16+k], acc);
    cpart[c][q] = acc;
  }
  __syncthreads();
  if (d < NC_){
    float acc = cb[d];
    #pragma unroll
    for (int q=0;q<16;q++) acc += cpart[d][q];
    out[b*NC_ + d] = acc;
  }
}

extern "C" void kernel_launch(void* const* d_in, const int* in_sizes, int n_in,
                              void* d_out, int out_size, void* d_ws, size_t ws_size,
                              hipStream_t stream){
  const float* emb   = (const float*)d_in[0];
  const float* pos   = (const float*)d_in[1];
  const float* ln_w  = (const float*)d_in[2];
  const float* ln_b  = (const float*)d_in[3];
  const float* ipw   = (const float*)d_in[4];
  const float* cw    = (const float*)d_in[5];
  const float* cb    = (const float*)d_in[6];
  const float* xpw   = (const float*)d_in[7];
  const float* dtw   = (const float*)d_in[8];
  const float* dtb   = (const float*)d_in[9];
  const float* A_log = (const float*)d_in[10];
  const float* Dp    = (const float*)d_in[11];
  const float* opw   = (const float*)d_in[12];
  const float* nw    = (const float*)d_in[13];
  const float* nb    = (const float*)d_in[14];
  const float* clw   = (const float*)d_in[15];
  const float* clb   = (const float*)d_in[16];
  const int*   ids   = (const int*)d_in[17];
  const int*   mask  = (const int*)d_in[18];
  float* out = (float*)d_out;

  float* ws   = (float*)d_ws;
  float* h    = ws;               // 2048*256
  float* xz   = h    + 524288;    // 2048*1024
  float* xc   = xz   + 2097152;   // 2048*512
  float* xdbl = xc   + 1048576;   // 2048*48
  float* delta= xdbl + 98304;     // 2048*512
  float* part = delta+ 1048576;   // 2*8*256
  float* pcnt = part + 4096;      // 16
  float* cpA  = pcnt + 16;        // NCH*NCHAIN
  float* slocA= cpA  + 1048576;
  float* hlocA= slocA+ 1048576;
  float* s0A  = hlocA+ 1048576;
  float* h0A  = s0A  + 1048576;
  ushort_t* hnb  = (ushort_t*)(h0A + 1048576); // 2048*256 bf16
  ushort_t* y2b  = hnb + 524288;               // 2048*512 bf16
  ushort_t* ipwb = y2b + 1048576;              // 6*1024*256 bf16
  ushort_t* opwb = ipwb + 1572864;             // 6*256*512 bf16

  // one-time (per call) weight conversion
  k_cvt<<<dim3(1536), 256, 0, stream>>>(ipw, ipwb, 6*2*DI_*DM);
  k_cvt<<<dim3(768),  256, 0, stream>>>(opw, opwb, 6*DM*DI_);

  k_embed<<<dim3(B_*L_), dim3(DM), 0, stream>>>(emb, pos, ids, h);
  for (int l=0; l<NL_; ++l){
    k_ln<<<dim3(B_*L_), dim3(DM), 0, stream>>>(h, hnb, ln_w + l*DM, ln_b + l*DM);
    k_gemm_bf<false><<<dim3((2*DI_)/64, (B_*L_)/64), 256, 0, stream>>>(
        hnb, ipwb + (size_t)l*2*DI_*DM, nullptr, xz, B_*L_, 2*DI_, DM);
    k_conv<<<dim3((B_*L_*DI_)/256), 256, 0, stream>>>(xz, cw + l*DI_*DC_, cb + l*DI_, xc);
    k_xproj_dt<<<dim3(B_*L_), 256, 0, stream>>>(
        xc, xpw + (size_t)l*48*DI_, dtw + (size_t)l*DI_*16, dtb + l*DI_, xdbl, delta);
    k_scanA<<<dim3(NCH, DI_/16, B_), 256, 0, stream>>>(
        delta, xc, xdbl, A_log + (size_t)l*DI_*DS_, cpA, slocA, hlocA);
    k_scanB<<<dim3(NCHAIN/256), 256, 0, stream>>>(cpA, slocA, hlocA, s0A, h0A);
    k_scanC<<<dim3(NCH, DI_/16, B_), 256, 0, stream>>>(
        delta, xc, xdbl, xz, A_log + (size_t)l*DI_*DS_, Dp + l*DI_, s0A, h0A, y2b);
    k_gemm_bf<true><<<dim3(DM/64, (B_*L_)/64), 256, 0, stream>>>(
        y2b, opwb + (size_t)l*DM*DI_, h, h, B_*L_, DM, DI_);
  }
  k_pool<<<dim3(8, B_), DM, 0, stream>>>(h, mask, part, pcnt);
  k_head<<<dim3(B_), DM, 0, stream>>>(part, pcnt, nw, nb, clw, clb, out);
}

// Round 4
// 544.100 us; speedup vs baseline: 3.8498x; 1.2348x over previous
//
#include <hip/hip_runtime.h>
#include <math.h>

#define B_ 2
#define L_ 1024
#define DM 256
#define NL_ 6
#define DI_ 512
#define DS_ 16
#define DC_ 4
#define NC_ 10
#define ALPHA_ 0.1f
#define LC 32
#define NCH (L_/LC)            // 32 chunks
#define NCHAIN (B_*DI_*DS_)    // 16384 chains
#define BETA_LC 0.034336838202925124f  // 0.9^32

typedef unsigned short ushort_t;
typedef __attribute__((ext_vector_type(8))) short s16x8;      // 8 bf16 (MFMA A/B frag)
typedef __attribute__((ext_vector_type(4))) float f32x4;      // MFMA C/D frag
typedef __attribute__((ext_vector_type(8))) unsigned short u16x8;

__device__ __forceinline__ float sigmoidf_(float x){ return 1.f/(1.f+__expf(-x)); }
__device__ __forceinline__ ushort_t f2bf(float f){
  union{float f;unsigned u;} c; c.f=f; unsigned u=c.u;
  return (ushort_t)((u + 0x7fffu + ((u>>16)&1u))>>16);
}
__device__ __forceinline__ float bf2f(ushort_t h){
  union{unsigned u;float f;} c; c.u = ((unsigned)h)<<16; return c.f;
}

// ---------------- embed ----------------
__global__ void k_embed(const float* __restrict__ emb, const float* __restrict__ pos,
                        const int* __restrict__ ids, float* __restrict__ h){
  int row = blockIdx.x;
  int t = row & (L_-1);
  int d = threadIdx.x;
  int v = ids[row];
  h[(size_t)row*DM + d] = emb[(size_t)v*DM + d] + pos[(size_t)t*DM + d];
}

// ---------------- fp32 -> bf16 weight conversion ----------------
__global__ void k_cvt(const float* __restrict__ in, ushort_t* __restrict__ o, int n){
  int i = (blockIdx.x*256 + threadIdx.x)*4;
  if (i < n){
    float4 v = *reinterpret_cast<const float4*>(&in[i]);
    ushort4 r;
    r.x = f2bf(v.x); r.y = f2bf(v.y); r.z = f2bf(v.z); r.w = f2bf(v.w);
    *reinterpret_cast<ushort4*>(&o[i]) = r;
  }
}

// ---------------- fused LN + in_proj GEMM (bf16 MFMA), writes xz bf16 ----------------
// C[M,1024] = LN(h)[M,256] @ W[1024,256]^T ; 64x64 tile, full-K single stage.
__global__ __launch_bounds__(256) void k_gemm_ln(const float* __restrict__ h,
    const ushort_t* __restrict__ W, const float* __restrict__ lw,
    const float* __restrict__ lb, ushort_t* __restrict__ xzb){
  __shared__ ushort_t As[64][264];   // 256 + 8 pad -> 2-way bank alias (free)
  __shared__ ushort_t Ws[64][264];
  int bm = blockIdx.y<<6, bn = blockIdx.x<<6;
  int tid = threadIdx.x;
  {
    int r = tid>>2, q = tid&3;       // 4 threads per row, 64 elems each
    const float* src = &h[(size_t)(bm+r)*DM + q*64];
    float4 v[16]; float s1=0.f, s2=0.f;
    #pragma unroll
    for (int i=0;i<16;i++){
      v[i] = *reinterpret_cast<const float4*>(src + i*4);
      s1 += v[i].x+v[i].y+v[i].z+v[i].w;
      s2 += v[i].x*v[i].x+v[i].y*v[i].y+v[i].z*v[i].z+v[i].w*v[i].w;
    }
    s1 += __shfl_xor(s1,1); s2 += __shfl_xor(s2,1);
    s1 += __shfl_xor(s1,2); s2 += __shfl_xor(s2,2);
    float mean = s1*(1.f/DM);
    float rstd = rsqrtf(s2*(1.f/DM) - mean*mean + 1e-5f);
    #pragma unroll
    for (int i=0;i<16;i++){
      int c = q*64 + i*4;
      ushort4 o;
      o.x = f2bf((v[i].x-mean)*rstd*lw[c+0]+lb[c+0]);
      o.y = f2bf((v[i].y-mean)*rstd*lw[c+1]+lb[c+1]);
      o.z = f2bf((v[i].z-mean)*rstd*lw[c+2]+lb[c+2]);
      o.w = f2bf((v[i].w-mean)*rstd*lw[c+3]+lb[c+3]);
      *reinterpret_cast<ushort4*>(&As[r][c]) = o;
    }
    const ushort_t* ws = &W[(size_t)(bn+r)*DM + q*64];
    #pragma unroll
    for (int i=0;i<8;i++)
      *reinterpret_cast<u16x8*>(&Ws[r][q*64+i*8]) = *reinterpret_cast<const u16x8*>(ws + i*8);
  }
  __syncthreads();
  int lane = tid&63, wid = tid>>6;
  int wm = (wid>>1)<<5, wn = (wid&1)<<5;
  int fr = lane&15, fk = (lane>>4)<<3;
  f32x4 acc[2][2] = {};
  #pragma unroll
  for (int k0=0;k0<DM;k0+=32){
    s16x8 a0 = *reinterpret_cast<const s16x8*>(&As[wm+fr][k0+fk]);
    s16x8 a1 = *reinterpret_cast<const s16x8*>(&As[wm+16+fr][k0+fk]);
    s16x8 b0 = *reinterpret_cast<const s16x8*>(&Ws[wn+fr][k0+fk]);
    s16x8 b1 = *reinterpret_cast<const s16x8*>(&Ws[wn+16+fr][k0+fk]);
    acc[0][0] = __builtin_amdgcn_mfma_f32_16x16x32_bf16(a0,b0,acc[0][0],0,0,0);
    acc[0][1] = __builtin_amdgcn_mfma_f32_16x16x32_bf16(a0,b1,acc[0][1],0,0,0);
    acc[1][0] = __builtin_amdgcn_mfma_f32_16x16x32_bf16(a1,b0,acc[1][0],0,0,0);
    acc[1][1] = __builtin_amdgcn_mfma_f32_16x16x32_bf16(a1,b1,acc[1][1],0,0,0);
  }
  int cr = (lane>>4)<<2, cc = lane&15;
  #pragma unroll
  for (int i=0;i<2;i++)
    #pragma unroll
    for (int j=0;j<2;j++){
      int row = bm + wm + (i<<4) + cr;
      int col = bn + wn + (j<<4) + cc;
      #pragma unroll
      for (int r=0;r<4;r++)
        xzb[(size_t)(row+r)*(2*DI_) + col] = f2bf(acc[i][j][r]);
    }
}

// ---------------- fused conv+SiLU + x_proj + dt_proj + softplus (4 rows/block) ----------------
__global__ __launch_bounds__(256) void k_xpc(const ushort_t* __restrict__ xzb,
    const float* __restrict__ cw, const float* __restrict__ cb,
    const float* __restrict__ xw, const float* __restrict__ dtw,
    const float* __restrict__ dtb, float* __restrict__ xc,
    float* __restrict__ xdbl, float* __restrict__ delta){
  __shared__ float sxz[7][DI_];
  __shared__ float sx[4][DI_];
  __shared__ float sdbl[4][48];
  int tid = threadIdx.x;
  int m0 = blockIdx.x*4;
  #pragma unroll
  for (int idx=0; idx<14; ++idx){
    int flat = idx*256 + tid;            // 7*512 = 3584
    int i = flat>>9, d = flat&511;
    int mr = m0 - 3 + i;
    sxz[i][d] = (mr>=0) ? bf2f(xzb[(size_t)mr*(2*DI_) + d]) : 0.f;
  }
  __syncthreads();
  #pragma unroll
  for (int idx=0; idx<8; ++idx){
    int flat = idx*256 + tid;            // 4*512 = 2048
    int r = flat>>9, d = flat&511;
    int t = (m0 + r) & (L_-1);
    float acc = cb[d];
    #pragma unroll
    for (int k=0;k<4;k++)
      if (t-3+k >= 0) acc = fmaf(cw[d*4+k], sxz[r+k][d], acc);
    float sv = acc * sigmoidf_(acc);
    sx[r][d] = sv;
    xc[(size_t)(m0+r)*DI_ + d] = sv;
  }
  __syncthreads();
  if (tid < 192){
    int o = tid>>2, q = tid&3;           // 48 outputs x 4 K-quarters
    const float* wp = &xw[(size_t)o*DI_ + q*128];
    float a0=0.f,a1=0.f,a2=0.f,a3=0.f;
    #pragma unroll 8
    for (int k4=0;k4<32;k4++){
      float4 wv = *reinterpret_cast<const float4*>(wp + k4*4);
      int kk = q*128 + k4*4;
      float4 x0 = *reinterpret_cast<const float4*>(&sx[0][kk]);
      float4 x1 = *reinterpret_cast<const float4*>(&sx[1][kk]);
      float4 x2 = *reinterpret_cast<const float4*>(&sx[2][kk]);
      float4 x3 = *reinterpret_cast<const float4*>(&sx[3][kk]);
      a0 = fmaf(x0.x,wv.x,a0); a0 = fmaf(x0.y,wv.y,a0); a0 = fmaf(x0.z,wv.z,a0); a0 = fmaf(x0.w,wv.w,a0);
      a1 = fmaf(x1.x,wv.x,a1); a1 = fmaf(x1.y,wv.y,a1); a1 = fmaf(x1.z,wv.z,a1); a1 = fmaf(x1.w,wv.w,a1);
      a2 = fmaf(x2.x,wv.x,a2); a2 = fmaf(x2.y,wv.y,a2); a2 = fmaf(x2.z,wv.z,a2); a2 = fmaf(x2.w,wv.w,a2);
      a3 = fmaf(x3.x,wv.x,a3); a3 = fmaf(x3.y,wv.y,a3); a3 = fmaf(x3.z,wv.z,a3); a3 = fmaf(x3.w,wv.w,a3);
    }
    a0 += __shfl_xor(a0,1); a0 += __shfl_xor(a0,2);
    a1 += __shfl_xor(a1,1); a1 += __shfl_xor(a1,2);
    a2 += __shfl_xor(a2,1); a2 += __shfl_xor(a2,2);
    a3 += __shfl_xor(a3,1); a3 += __shfl_xor(a3,2);
    if (q==0){
      sdbl[0][o]=a0; sdbl[1][o]=a1; sdbl[2][o]=a2; sdbl[3][o]=a3;
      xdbl[(size_t)(m0+0)*48+o]=a0;
      xdbl[(size_t)(m0+1)*48+o]=a1;
      xdbl[(size_t)(m0+2)*48+o]=a2;
      xdbl[(size_t)(m0+3)*48+o]=a3;
    }
  }
  __syncthreads();
  #pragma unroll
  for (int idx=0; idx<8; ++idx){
    int flat = idx*256 + tid;
    int r = flat>>9, n = flat&511;
    const float4* wp = reinterpret_cast<const float4*>(&dtw[n*16]);
    float4 w0=wp[0], w1=wp[1], w2=wp[2], w3=wp[3];
    const float* sd = sdbl[r];
    float acc = dtb[n];
    acc = fmaf(sd[0],w0.x,acc);  acc = fmaf(sd[1],w0.y,acc);
    acc = fmaf(sd[2],w0.z,acc);  acc = fmaf(sd[3],w0.w,acc);
    acc = fmaf(sd[4],w1.x,acc);  acc = fmaf(sd[5],w1.y,acc);
    acc = fmaf(sd[6],w1.z,acc);  acc = fmaf(sd[7],w1.w,acc);
    acc = fmaf(sd[8],w2.x,acc);  acc = fmaf(sd[9],w2.y,acc);
    acc = fmaf(sd[10],w2.z,acc); acc = fmaf(sd[11],w2.w,acc);
    acc = fmaf(sd[12],w3.x,acc); acc = fmaf(sd[13],w3.y,acc);
    acc = fmaf(sd[14],w3.z,acc); acc = fmaf(sd[15],w3.w,acc);
    delta[(size_t)(m0+r)*DI_ + n] = (acc>20.f)? acc : log1pf(__expf(acc));
  }
}

// ================= chunked parallel scan (LC=32) =================
__global__ __launch_bounds__(256) void k_scanA(const float* __restrict__ delta,
    const float* __restrict__ xc, const float* __restrict__ xdbl,
    const float* __restrict__ A_log, float* __restrict__ cpArr,
    float* __restrict__ slocArr, float* __restrict__ hlocArr){
  int j = blockIdx.x, g = blockIdx.y, b = blockIdx.z;
  int tid = threadIdx.x;
  int n = tid&15, dg = tid>>4;
  int d0 = g*16;
  __shared__ float sdel[LC][16], sxv[LC][16], sB[LC][16];
  #pragma unroll
  for (int idx=0; idx<2; ++idx){
    int flat = idx*256 + tid;
    int t = flat>>4, c = flat&15;
    int m = b*L_ + j*LC + t;
    sdel[t][c] = delta[(size_t)m*DI_ + d0 + c];
    sxv[t][c]  = xc  [(size_t)m*DI_ + d0 + c];
    sB[t][c]   = xdbl[(size_t)m*48 + 16 + c];
  }
  __syncthreads();
  float a = -__expf(A_log[(d0+dg)*DS_ + n]);
  float dA[LC], dBu[LC];
  #pragma unroll
  for (int t=0;t<LC;t++){
    float dv = sdel[t][dg];
    dA[t]  = __expf(dv*a);
    dBu[t] = dv * sxv[t][dg] * sB[t][n];
  }
  float hs=0.f, hh=0.f, cp=1.f;
  #pragma unroll
  for (int t=0;t<LC;t++){
    float mix = fmaf(ALPHA_, hs-hh, hh);
    hs = fmaf(dA[t], hs, dBu[t]);
    hh = fmaf(dA[t], mix, dBu[t]);
    cp *= dA[t];
  }
  size_t o = (size_t)j*NCHAIN + (size_t)(b*DI_+d0)*DS_ + tid;
  cpArr[o]=cp; slocArr[o]=hs; hlocArr[o]=hh;
}

// Pass C: inline chunk-combine (redundant lookback) + re-run + gate, writes y2 bf16
__global__ __launch_bounds__(256) void k_scanC(const float* __restrict__ delta,
    const float* __restrict__ xc, const float* __restrict__ xdbl,
    const ushort_t* __restrict__ xzb, const float* __restrict__ A_log,
    const float* __restrict__ Dp, const float* __restrict__ cpArr,
    const float* __restrict__ slocArr, const float* __restrict__ hlocArr,
    ushort_t* __restrict__ y2b){
  int j = blockIdx.x, g = blockIdx.y, b = blockIdx.z;
  int tid = threadIdx.x;
  int n = tid&15, dg = tid>>4;
  int d0 = g*16;
  __shared__ float sdel[LC][16], sxv[LC][16], sB[LC][16], sC[LC][16], sz[LC][16], sy[LC][16];
  #pragma unroll
  for (int idx=0; idx<2; ++idx){
    int flat = idx*256 + tid;
    int t = flat>>4, c = flat&15;
    int m = b*L_ + j*LC + t;
    sdel[t][c] = delta[(size_t)m*DI_ + d0 + c];
    sxv[t][c]  = xc  [(size_t)m*DI_ + d0 + c];
    sB[t][c]   = xdbl[(size_t)m*48 + 16 + c];
    sC[t][c]   = xdbl[(size_t)m*48 + 32 + c];
    sz[t][c]   = bf2f(xzb[(size_t)m*(2*DI_) + DI_ + d0 + c]);
  }
  // inline combine of chunks 0..j-1 (global loads, independent of LDS)
  int chain = (b*DI_+d0)*DS_ + tid;
  float hs=0.f, hh=0.f;
  #pragma unroll 4
  for (int jj=0; jj<j; ++jj){
    size_t o = (size_t)jj*NCHAIN + chain;
    float cp = cpArr[o], sl = slocArr[o], hl = hlocArr[o];
    float snew = fmaf(cp, hs, sl);
    hh = fmaf(cp, fmaf(BETA_LC, hh-hs, hs), hl);
    hs = snew;
  }
  __syncthreads();
  float a = -__expf(A_log[(d0+dg)*DS_ + n]);
  float dA[LC], dBu[LC];
  #pragma unroll
  for (int t=0;t<LC;t++){
    float dv = sdel[t][dg];
    dA[t]  = __expf(dv*a);
    dBu[t] = dv * sxv[t][dg] * sB[t][n];
  }
  float yv[LC];
  #pragma unroll
  for (int t=0;t<LC;t++){
    float mix = fmaf(ALPHA_, hs-hh, hh);
    hs = fmaf(dA[t], hs, dBu[t]);
    hh = fmaf(dA[t], mix, dBu[t]);
    yv[t] = hh * sC[t][n];
  }
  #pragma unroll
  for (int t=0;t<LC;t++){
    yv[t] += __shfl_xor(yv[t],1,16);
    yv[t] += __shfl_xor(yv[t],2,16);
    yv[t] += __shfl_xor(yv[t],4,16);
    yv[t] += __shfl_xor(yv[t],8,16);
  }
  if (n==0){
    #pragma unroll
    for (int t=0;t<LC;t++) sy[t][dg] = yv[t];
  }
  __syncthreads();
  float dpv = Dp[d0 + (tid&15)];
  #pragma unroll
  for (int idx=0; idx<2; ++idx){
    int flat = idx*256 + tid;
    int t2 = flat>>4, dd = flat&15;
    float xvv = sxv[t2][dd];
    float zv  = sz [t2][dd];
    float yfin = (sy[t2][dd] + dpv*xvv) * (zv*sigmoidf_(zv));
    y2b[(size_t)(b*L_ + j*LC + t2)*DI_ + d0 + dd] = f2bf(yfin);
  }
}

// ---------------- out_proj GEMM (bf16 MFMA) + residual, h += y2 @ W^T ----------------
// BM=32, BN=64, K=512 in two BK=256 stages.
__global__ __launch_bounds__(256) void k_gemm_out(const ushort_t* __restrict__ A,
    const ushort_t* __restrict__ W, float* __restrict__ h){
  __shared__ ushort_t As[32][264];
  __shared__ ushort_t Ws[64][264];
  int bm = blockIdx.y<<5, bn = blockIdx.x<<6;
  int tid = threadIdx.x;
  int lane = tid&63, wid = tid>>6;
  int wm = (wid>>1)<<4, wn = (wid&1)<<5;
  int fr = lane&15, fk = (lane>>4)<<3;
  f32x4 acc[2] = {};
  for (int k0=0;k0<DI_;k0+=256){
    {
      int r = tid>>3, q = tid&7;
      const ushort_t* src = &A[(size_t)(bm+r)*DI_ + k0 + q*32];
      #pragma unroll
      for (int i=0;i<4;i++)
        *reinterpret_cast<u16x8*>(&As[r][q*32+i*8]) = *reinterpret_cast<const u16x8*>(src+i*8);
      int r2 = tid>>2, q2 = tid&3;
      const ushort_t* ws = &W[(size_t)(bn+r2)*DI_ + k0 + q2*64];
      #pragma unroll
      for (int i=0;i<8;i++)
        *reinterpret_cast<u16x8*>(&Ws[r2][q2*64+i*8]) = *reinterpret_cast<const u16x8*>(ws+i*8);
    }
    __syncthreads();
    #pragma unroll
    for (int k=0;k<256;k+=32){
      s16x8 a0 = *reinterpret_cast<const s16x8*>(&As[wm+fr][k+fk]);
      s16x8 b0 = *reinterpret_cast<const s16x8*>(&Ws[wn+fr][k+fk]);
      s16x8 b1 = *reinterpret_cast<const s16x8*>(&Ws[wn+16+fr][k+fk]);
      acc[0] = __builtin_amdgcn_mfma_f32_16x16x32_bf16(a0,b0,acc[0],0,0,0);
      acc[1] = __builtin_amdgcn_mfma_f32_16x16x32_bf16(a0,b1,acc[1],0,0,0);
    }
    __syncthreads();
  }
  int cr = (lane>>4)<<2, cc = lane&15;
  #pragma unroll
  for (int jj=0;jj<2;jj++){
    int row = bm + wm + cr;
    int col = bn + wn + (jj<<4) + cc;
    #pragma unroll
    for (int r=0;r<4;r++){
      size_t idx2 = (size_t)(row+r)*DM + col;
      h[idx2] += acc[jj][r];
    }
  }
}

// ---------------- fused masked pool + LN + classifier ----------------
__global__ __launch_bounds__(1024) void k_poolhead(const float* __restrict__ h,
    const int* __restrict__ mask, const float* __restrict__ nw, const float* __restrict__ nb,
    const float* __restrict__ cw, const float* __restrict__ cb, float* __restrict__ out){
  int b = blockIdx.x, tid = threadIdx.x;
  int d = tid&255, c = tid>>8;   // 4 t-chunks
  __shared__ float psum[4][DM];
  __shared__ float pcs[4];
  float s = 0.f;
  for (int t=c*256; t<(c+1)*256; ++t)
    s = fmaf((float)mask[b*L_+t], h[(size_t)(b*L_+t)*DM+d], s);
  psum[c][d] = s;
  if (d==0){
    int cc2=0;
    for (int t=c*256;t<(c+1)*256;++t) cc2 += mask[b*L_+t];
    pcs[c] = (float)cc2;
  }
  __syncthreads();
  float v = 0.f;
  if (tid < 256)
    v = (psum[0][d]+psum[1][d]+psum[2][d]+psum[3][d]) /
        (pcs[0]+pcs[1]+pcs[2]+pcs[3]);
  float s1 = (tid<256)? v:0.f, s2 = (tid<256)? v*v:0.f;
  #pragma unroll
  for (int o=32;o>0;o>>=1){ s1 += __shfl_down(s1,o); s2 += __shfl_down(s2,o); }
  __shared__ float a1[16], a2[16];
  __shared__ float mv[2];
  int wv2 = tid>>6, lane = tid&63;
  if (lane==0){ a1[wv2]=s1; a2[wv2]=s2; }
  __syncthreads();
  if (tid==0){
    float t1=0.f,t2=0.f;
    #pragma unroll
    for (int i2=0;i2<16;i2++){ t1+=a1[i2]; t2+=a2[i2]; }
    float m = t1/(float)DM;
    mv[0]=m; mv[1]=rsqrtf(t2/(float)DM - m*m + 1e-5f);
  }
  __syncthreads();
  __shared__ float sp[DM];
  if (tid<256) sp[d] = (v-mv[0])*mv[1]*nw[d]+nb[d];
  __syncthreads();
  __shared__ float cpart[NC_][16];
  if (tid < NC_*16){
    int cc3 = tid>>4, q = tid&15;
    float acc2 = 0.f;
    #pragma unroll
    for (int k=0;k<16;k++) acc2 = fmaf(sp[q*16+k], cw[(size_t)cc3*DM+q*16+k], acc2);
    cpart[cc3][q] = acc2;
  }
  __syncthreads();
  if (tid < NC_){
    float acc2 = cb[tid];
    #pragma unroll
    for (int q=0;q<16;q++) acc2 += cpart[tid][q];
    out[b*NC_+tid] = acc2;
  }
}

extern "C" void kernel_launch(void* const* d_in, const int* in_sizes, int n_in,
                              void* d_out, int out_size, void* d_ws, size_t ws_size,
                              hipStream_t stream){
  const float* emb   = (const float*)d_in[0];
  const float* pos   = (const float*)d_in[1];
  const float* ln_w  = (const float*)d_in[2];
  const float* ln_b  = (const float*)d_in[3];
  const float* ipw   = (const float*)d_in[4];
  const float* cw    = (const float*)d_in[5];
  const float* cb    = (const float*)d_in[6];
  const float* xpw   = (const float*)d_in[7];
  const float* dtw   = (const float*)d_in[8];
  const float* dtb   = (const float*)d_in[9];
  const float* A_log = (const float*)d_in[10];
  const float* Dp    = (const float*)d_in[11];
  const float* opw   = (const float*)d_in[12];
  const float* nw    = (const float*)d_in[13];
  const float* nb    = (const float*)d_in[14];
  const float* clw   = (const float*)d_in[15];
  const float* clb   = (const float*)d_in[16];
  const int*   ids   = (const int*)d_in[17];
  const int*   mask  = (const int*)d_in[18];
  float* out = (float*)d_out;

  float* ws    = (float*)d_ws;
  float* h     = ws;                    // 2048*256
  float* xc    = h + 524288;            // 2048*512
  float* xdbl  = xc + 1048576;          // 2048*48
  float* delta = xdbl + 98304;          // 2048*512
  float* cpA   = delta + 1048576;       // 32*16384
  float* slocA = cpA + 524288;
  float* hlocA = slocA + 524288;
  ushort_t* xzb  = (ushort_t*)(hlocA + 524288);  // 2048*1024 bf16
  ushort_t* y2b  = xzb + 2097152;                // 2048*512 bf16
  ushort_t* ipwb = y2b + 1048576;                // 6*1024*256 bf16
  ushort_t* opwb = ipwb + 1572864;               // 6*256*512 bf16

  k_cvt<<<dim3(1536), 256, 0, stream>>>(ipw, ipwb, 6*2*DI_*DM);
  k_cvt<<<dim3(768),  256, 0, stream>>>(opw, opwb, 6*DM*DI_);
  k_embed<<<dim3(B_*L_), dim3(DM), 0, stream>>>(emb, pos, ids, h);

  for (int l=0; l<NL_; ++l){
    k_gemm_ln<<<dim3(16, 32), 256, 0, stream>>>(
        h, ipwb + (size_t)l*2*DI_*DM, ln_w + l*DM, ln_b + l*DM, xzb);
    k_xpc<<<dim3((B_*L_)/4), 256, 0, stream>>>(
        xzb, cw + l*DI_*DC_, cb + l*DI_, xpw + (size_t)l*48*DI_,
        dtw + (size_t)l*DI_*16, dtb + l*DI_, xc, xdbl, delta);
    k_scanA<<<dim3(NCH, DI_/16, B_), 256, 0, stream>>>(
        delta, xc, xdbl, A_log + (size_t)l*DI_*DS_, cpA, slocA, hlocA);
    k_scanC<<<dim3(NCH, DI_/16, B_), 256, 0, stream>>>(
        delta, xc, xdbl, xzb, A_log + (size_t)l*DI_*DS_, Dp + l*DI_,
        cpA, slocA, hlocA, y2b);
    k_gemm_out<<<dim3(DM/64, (B_*L_)/32), 256, 0, stream>>>(
        y2b, opwb + (size_t)l*DM*DI_, h);
  }
  k_poolhead<<<dim3(B_), 1024, 0, stream>>>(h, mask, nw, nb, clw, clb, out);
}

// Round 5
// 479.060 us; speedup vs baseline: 4.3724x; 1.1358x over previous
//
#include <hip/hip_runtime.h>
#include <math.h>

#define B_ 2
#define L_ 1024
#define DM 256
#define NL_ 6
#define DI_ 512
#define DS_ 16
#define DC_ 4
#define NC_ 10
#define ALPHA_ 0.1f
#define LC 32
#define NCH (L_/LC)            // 32 chunks
#define NCHAIN (B_*DI_*DS_)    // 16384 chains
#define BETA_LC 0.034336838202925124f  // 0.9^32

typedef unsigned short ushort_t;
typedef __attribute__((ext_vector_type(8))) short s16x8;      // 8 bf16 (MFMA A/B frag)
typedef __attribute__((ext_vector_type(4))) float f32x4;      // MFMA C/D frag
typedef __attribute__((ext_vector_type(8))) unsigned short u16x8;

__device__ __forceinline__ float sigmoidf_(float x){ return 1.f/(1.f+__expf(-x)); }
__device__ __forceinline__ ushort_t f2bf(float f){
  union{float f;unsigned u;} c; c.f=f; unsigned u=c.u;
  return (ushort_t)((u + 0x7fffu + ((u>>16)&1u))>>16);
}
__device__ __forceinline__ float bf2f(ushort_t h){
  union{unsigned u;float f;} c; c.u = ((unsigned)h)<<16; return c.f;
}

// ---------------- embed ----------------
__global__ void k_embed(const float* __restrict__ emb, const float* __restrict__ pos,
                        const int* __restrict__ ids, float* __restrict__ h){
  int row = blockIdx.x;
  int t = row & (L_-1);
  int d = threadIdx.x;
  int v = ids[row];
  h[(size_t)row*DM + d] = emb[(size_t)v*DM + d] + pos[(size_t)t*DM + d];
}

// ---------------- fp32 -> bf16 weight conversion ----------------
__global__ void k_cvt(const float* __restrict__ in, ushort_t* __restrict__ o, int n){
  int i = (blockIdx.x*256 + threadIdx.x)*4;
  if (i < n){
    float4 v = *reinterpret_cast<const float4*>(&in[i]);
    ushort4 r;
    r.x = f2bf(v.x); r.y = f2bf(v.y); r.z = f2bf(v.z); r.w = f2bf(v.w);
    *reinterpret_cast<ushort4*>(&o[i]) = r;
  }
}

// ---------------- fused LN + in_proj GEMM (bf16 MFMA), writes xz bf16 ----------------
__global__ __launch_bounds__(256) void k_gemm_ln(const float* __restrict__ h,
    const ushort_t* __restrict__ W, const float* __restrict__ lw,
    const float* __restrict__ lb, ushort_t* __restrict__ xzb){
  __shared__ ushort_t As[64][264];   // 256 + 8 pad -> 2-way bank alias (free)
  __shared__ ushort_t Ws[64][264];
  int bm = blockIdx.y<<6, bn = blockIdx.x<<6;
  int tid = threadIdx.x;
  {
    int r = tid>>2, q = tid&3;       // 4 threads per row, 64 elems each
    const float* src = &h[(size_t)(bm+r)*DM + q*64];
    float4 v[16]; float s1=0.f, s2=0.f;
    #pragma unroll
    for (int i=0;i<16;i++){
      v[i] = *reinterpret_cast<const float4*>(src + i*4);
      s1 += v[i].x+v[i].y+v[i].z+v[i].w;
      s2 += v[i].x*v[i].x+v[i].y*v[i].y+v[i].z*v[i].z+v[i].w*v[i].w;
    }
    s1 += __shfl_xor(s1,1); s2 += __shfl_xor(s2,1);
    s1 += __shfl_xor(s1,2); s2 += __shfl_xor(s2,2);
    float mean = s1*(1.f/DM);
    float rstd = rsqrtf(s2*(1.f/DM) - mean*mean + 1e-5f);
    #pragma unroll
    for (int i=0;i<16;i++){
      int c = q*64 + i*4;
      ushort4 o;
      o.x = f2bf((v[i].x-mean)*rstd*lw[c+0]+lb[c+0]);
      o.y = f2bf((v[i].y-mean)*rstd*lw[c+1]+lb[c+1]);
      o.z = f2bf((v[i].z-mean)*rstd*lw[c+2]+lb[c+2]);
      o.w = f2bf((v[i].w-mean)*rstd*lw[c+3]+lb[c+3]);
      *reinterpret_cast<ushort4*>(&As[r][c]) = o;
    }
    const ushort_t* ws = &W[(size_t)(bn+r)*DM + q*64];
    #pragma unroll
    for (int i=0;i<8;i++)
      *reinterpret_cast<u16x8*>(&Ws[r][q*64+i*8]) = *reinterpret_cast<const u16x8*>(ws + i*8);
  }
  __syncthreads();
  int lane = tid&63, wid = tid>>6;
  int wm = (wid>>1)<<5, wn = (wid&1)<<5;
  int fr = lane&15, fk = (lane>>4)<<3;
  f32x4 acc[2][2] = {};
  #pragma unroll
  for (int k0=0;k0<DM;k0+=32){
    s16x8 a0 = *reinterpret_cast<const s16x8*>(&As[wm+fr][k0+fk]);
    s16x8 a1 = *reinterpret_cast<const s16x8*>(&As[wm+16+fr][k0+fk]);
    s16x8 b0 = *reinterpret_cast<const s16x8*>(&Ws[wn+fr][k0+fk]);
    s16x8 b1 = *reinterpret_cast<const s16x8*>(&Ws[wn+16+fr][k0+fk]);
    acc[0][0] = __builtin_amdgcn_mfma_f32_16x16x32_bf16(a0,b0,acc[0][0],0,0,0);
    acc[0][1] = __builtin_amdgcn_mfma_f32_16x16x32_bf16(a0,b1,acc[0][1],0,0,0);
    acc[1][0] = __builtin_amdgcn_mfma_f32_16x16x32_bf16(a1,b0,acc[1][0],0,0,0);
    acc[1][1] = __builtin_amdgcn_mfma_f32_16x16x32_bf16(a1,b1,acc[1][1],0,0,0);
  }
  int cr = (lane>>4)<<2, cc = lane&15;
  #pragma unroll
  for (int i=0;i<2;i++)
    #pragma unroll
    for (int j=0;j<2;j++){
      int row = bm + wm + (i<<4) + cr;
      int col = bn + wn + (j<<4) + cc;
      #pragma unroll
      for (int r=0;r<4;r++)
        xzb[(size_t)(row+r)*(2*DI_) + col] = f2bf(acc[i][j][r]);
    }
}

// ---------------- fused conv+SiLU + x_proj + dt_proj + softplus (4 rows/block) ----------------
__global__ __launch_bounds__(256) void k_xpc(const ushort_t* __restrict__ xzb,
    const float* __restrict__ cw, const float* __restrict__ cb,
    const float* __restrict__ xw, const float* __restrict__ dtw,
    const float* __restrict__ dtb, float* __restrict__ xc,
    float* __restrict__ xdbl, float* __restrict__ delta){
  __shared__ float sxz[7][DI_];
  __shared__ float sx[4][DI_];
  __shared__ float sdbl[4][48];
  int tid = threadIdx.x;
  int m0 = blockIdx.x*4;
  #pragma unroll
  for (int idx=0; idx<14; ++idx){
    int flat = idx*256 + tid;            // 7*512 = 3584
    int i = flat>>9, d = flat&511;
    int mr = m0 - 3 + i;
    sxz[i][d] = (mr>=0) ? bf2f(xzb[(size_t)mr*(2*DI_) + d]) : 0.f;
  }
  __syncthreads();
  #pragma unroll
  for (int idx=0; idx<8; ++idx){
    int flat = idx*256 + tid;            // 4*512 = 2048
    int r = flat>>9, d = flat&511;
    int t = (m0 + r) & (L_-1);
    float acc = cb[d];
    #pragma unroll
    for (int k=0;k<4;k++)
      if (t-3+k >= 0) acc = fmaf(cw[d*4+k], sxz[r+k][d], acc);
    float sv = acc * sigmoidf_(acc);
    sx[r][d] = sv;
    xc[(size_t)(m0+r)*DI_ + d] = sv;
  }
  __syncthreads();
  if (tid < 192){
    int o = tid>>2, q = tid&3;           // 48 outputs x 4 K-quarters
    const float* wp = &xw[(size_t)o*DI_ + q*128];
    float a0=0.f,a1=0.f,a2=0.f,a3=0.f;
    #pragma unroll 8
    for (int k4=0;k4<32;k4++){
      float4 wv = *reinterpret_cast<const float4*>(wp + k4*4);
      int kk = q*128 + k4*4;
      float4 x0 = *reinterpret_cast<const float4*>(&sx[0][kk]);
      float4 x1 = *reinterpret_cast<const float4*>(&sx[1][kk]);
      float4 x2 = *reinterpret_cast<const float4*>(&sx[2][kk]);
      float4 x3 = *reinterpret_cast<const float4*>(&sx[3][kk]);
      a0 = fmaf(x0.x,wv.x,a0); a0 = fmaf(x0.y,wv.y,a0); a0 = fmaf(x0.z,wv.z,a0); a0 = fmaf(x0.w,wv.w,a0);
      a1 = fmaf(x1.x,wv.x,a1); a1 = fmaf(x1.y,wv.y,a1); a1 = fmaf(x1.z,wv.z,a1); a1 = fmaf(x1.w,wv.w,a1);
      a2 = fmaf(x2.x,wv.x,a2); a2 = fmaf(x2.y,wv.y,a2); a2 = fmaf(x2.z,wv.z,a2); a2 = fmaf(x2.w,wv.w,a2);
      a3 = fmaf(x3.x,wv.x,a3); a3 = fmaf(x3.y,wv.y,a3); a3 = fmaf(x3.z,wv.z,a3); a3 = fmaf(x3.w,wv.w,a3);
    }
    a0 += __shfl_xor(a0,1); a0 += __shfl_xor(a0,2);
    a1 += __shfl_xor(a1,1); a1 += __shfl_xor(a1,2);
    a2 += __shfl_xor(a2,1); a2 += __shfl_xor(a2,2);
    a3 += __shfl_xor(a3,1); a3 += __shfl_xor(a3,2);
    if (q==0){
      sdbl[0][o]=a0; sdbl[1][o]=a1; sdbl[2][o]=a2; sdbl[3][o]=a3;
      xdbl[(size_t)(m0+0)*48+o]=a0;
      xdbl[(size_t)(m0+1)*48+o]=a1;
      xdbl[(size_t)(m0+2)*48+o]=a2;
      xdbl[(size_t)(m0+3)*48+o]=a3;
    }
  }
  __syncthreads();
  #pragma unroll
  for (int idx=0; idx<8; ++idx){
    int flat = idx*256 + tid;
    int r = flat>>9, n = flat&511;
    const float4* wp = reinterpret_cast<const float4*>(&dtw[n*16]);
    float4 w0=wp[0], w1=wp[1], w2=wp[2], w3=wp[3];
    const float* sd = sdbl[r];
    float acc = dtb[n];
    acc = fmaf(sd[0],w0.x,acc);  acc = fmaf(sd[1],w0.y,acc);
    acc = fmaf(sd[2],w0.z,acc);  acc = fmaf(sd[3],w0.w,acc);
    acc = fmaf(sd[4],w1.x,acc);  acc = fmaf(sd[5],w1.y,acc);
    acc = fmaf(sd[6],w1.z,acc);  acc = fmaf(sd[7],w1.w,acc);
    acc = fmaf(sd[8],w2.x,acc);  acc = fmaf(sd[9],w2.y,acc);
    acc = fmaf(sd[10],w2.z,acc); acc = fmaf(sd[11],w2.w,acc);
    acc = fmaf(sd[12],w3.x,acc); acc = fmaf(sd[13],w3.y,acc);
    acc = fmaf(sd[14],w3.z,acc); acc = fmaf(sd[15],w3.w,acc);
    delta[(size_t)(m0+r)*DI_ + n] = (acc>20.f)? acc : log1pf(__expf(acc));
  }
}

// ================= chunked parallel scan (LC=32) =================
__global__ __launch_bounds__(256) void k_scanA(const float* __restrict__ delta,
    const float* __restrict__ xc, const float* __restrict__ xdbl,
    const float* __restrict__ A_log, float* __restrict__ cpArr,
    float* __restrict__ slocArr, float* __restrict__ hlocArr){
  int j = blockIdx.x, g = blockIdx.y, b = blockIdx.z;
  int tid = threadIdx.x;
  int n = tid&15, dg = tid>>4;
  int d0 = g*16;
  __shared__ float sdel[LC][16], sxv[LC][16], sB[LC][16];
  #pragma unroll
  for (int idx=0; idx<2; ++idx){
    int flat = idx*256 + tid;
    int t = flat>>4, c = flat&15;
    int m = b*L_ + j*LC + t;
    sdel[t][c] = delta[(size_t)m*DI_ + d0 + c];
    sxv[t][c]  = xc  [(size_t)m*DI_ + d0 + c];
    sB[t][c]   = xdbl[(size_t)m*48 + 16 + c];
  }
  __syncthreads();
  float a = -__expf(A_log[(d0+dg)*DS_ + n]);
  float dA[LC], dBu[LC];
  #pragma unroll
  for (int t=0;t<LC;t++){
    float dv = sdel[t][dg];
    dA[t]  = __expf(dv*a);
    dBu[t] = dv * sxv[t][dg] * sB[t][n];
  }
  float hs=0.f, hh=0.f, cp=1.f;
  #pragma unroll
  for (int t=0;t<LC;t++){
    float mix = fmaf(ALPHA_, hs-hh, hh);
    hs = fmaf(dA[t], hs, dBu[t]);
    hh = fmaf(dA[t], mix, dBu[t]);
    cp *= dA[t];
  }
  size_t o = (size_t)j*NCHAIN + (size_t)(b*DI_+d0)*DS_ + tid;
  cpArr[o]=cp; slocArr[o]=hs; hlocArr[o]=hh;
}

// Pass C: inline chunk-combine (redundant lookback) + re-run + gate, writes y2 bf16
__global__ __launch_bounds__(256) void k_scanC(const float* __restrict__ delta,
    const float* __restrict__ xc, const float* __restrict__ xdbl,
    const ushort_t* __restrict__ xzb, const float* __restrict__ A_log,
    const float* __restrict__ Dp, const float* __restrict__ cpArr,
    const float* __restrict__ slocArr, const float* __restrict__ hlocArr,
    ushort_t* __restrict__ y2b){
  int j = blockIdx.x, g = blockIdx.y, b = blockIdx.z;
  int tid = threadIdx.x;
  int n = tid&15, dg = tid>>4;
  int d0 = g*16;
  __shared__ float sdel[LC][16], sxv[LC][16], sB[LC][16], sC[LC][16], sz[LC][16], sy[LC][16];
  #pragma unroll
  for (int idx=0; idx<2; ++idx){
    int flat = idx*256 + tid;
    int t = flat>>4, c = flat&15;
    int m = b*L_ + j*LC + t;
    sdel[t][c] = delta[(size_t)m*DI_ + d0 + c];
    sxv[t][c]  = xc  [(size_t)m*DI_ + d0 + c];
    sB[t][c]   = xdbl[(size_t)m*48 + 16 + c];
    sC[t][c]   = xdbl[(size_t)m*48 + 32 + c];
    sz[t][c]   = bf2f(xzb[(size_t)m*(2*DI_) + DI_ + d0 + c]);
  }
  // inline combine of chunks 0..j-1 (global loads, independent of LDS)
  int chain = (b*DI_+d0)*DS_ + tid;
  float hs=0.f, hh=0.f;
  #pragma unroll 4
  for (int jj=0; jj<j; ++jj){
    size_t o = (size_t)jj*NCHAIN + chain;
    float cp = cpArr[o], sl = slocArr[o], hl = hlocArr[o];
    float snew = fmaf(cp, hs, sl);
    hh = fmaf(cp, fmaf(BETA_LC, hh-hs, hs), hl);
    hs = snew;
  }
  __syncthreads();
  float a = -__expf(A_log[(d0+dg)*DS_ + n]);
  float dA[LC], dBu[LC];
  #pragma unroll
  for (int t=0;t<LC;t++){
    float dv = sdel[t][dg];
    dA[t]  = __expf(dv*a);
    dBu[t] = dv * sxv[t][dg] * sB[t][n];
  }
  float yv[LC];
  #pragma unroll
  for (int t=0;t<LC;t++){
    float mix = fmaf(ALPHA_, hs-hh, hh);
    hs = fmaf(dA[t], hs, dBu[t]);
    hh = fmaf(dA[t], mix, dBu[t]);
    yv[t] = hh * sC[t][n];
  }
  #pragma unroll
  for (int t=0;t<LC;t++){
    yv[t] += __shfl_xor(yv[t],1,16);
    yv[t] += __shfl_xor(yv[t],2,16);
    yv[t] += __shfl_xor(yv[t],4,16);
    yv[t] += __shfl_xor(yv[t],8,16);
  }
  if (n==0){
    #pragma unroll
    for (int t=0;t<LC;t++) sy[t][dg] = yv[t];
  }
  __syncthreads();
  float dpv = Dp[d0 + (tid&15)];
  #pragma unroll
  for (int idx=0; idx<2; ++idx){
    int flat = idx*256 + tid;
    int t2 = flat>>4, dd = flat&15;
    float xvv = sxv[t2][dd];
    float zv  = sz [t2][dd];
    float yfin = (sy[t2][dd] + dpv*xvv) * (zv*sigmoidf_(zv));
    y2b[(size_t)(b*L_ + j*LC + t2)*DI_ + d0 + dd] = f2bf(yfin);
  }
}

// ---------------- out_proj GEMM (bf16 MFMA) + residual, h += y2 @ W^T ----------------
__global__ __launch_bounds__(256) void k_gemm_out(const ushort_t* __restrict__ A,
    const ushort_t* __restrict__ W, float* __restrict__ h){
  __shared__ ushort_t As[32][264];
  __shared__ ushort_t Ws[64][264];
  int bm = blockIdx.y<<5, bn = blockIdx.x<<6;
  int tid = threadIdx.x;
  int lane = tid&63, wid = tid>>6;
  int wm = (wid>>1)<<4, wn = (wid&1)<<5;
  int fr = lane&15, fk = (lane>>4)<<3;
  f32x4 acc[2] = {};
  for (int k0=0;k0<DI_;k0+=256){
    {
      int r = tid>>3, q = tid&7;
      const ushort_t* src = &A[(size_t)(bm+r)*DI_ + k0 + q*32];
      #pragma unroll
      for (int i=0;i<4;i++)
        *reinterpret_cast<u16x8*>(&As[r][q*32+i*8]) = *reinterpret_cast<const u16x8*>(src+i*8);
      int r2 = tid>>2, q2 = tid&3;
      const ushort_t* ws = &W[(size_t)(bn+r2)*DI_ + k0 + q2*64];
      #pragma unroll
      for (int i=0;i<8;i++)
        *reinterpret_cast<u16x8*>(&Ws[r2][q2*64+i*8]) = *reinterpret_cast<const u16x8*>(ws+i*8);
    }
    __syncthreads();
    #pragma unroll
    for (int k=0;k<256;k+=32){
      s16x8 a0 = *reinterpret_cast<const s16x8*>(&As[wm+fr][k+fk]);
      s16x8 b0 = *reinterpret_cast<const s16x8*>(&Ws[wn+fr][k+fk]);
      s16x8 b1 = *reinterpret_cast<const s16x8*>(&Ws[wn+16+fr][k+fk]);
      acc[0] = __builtin_amdgcn_mfma_f32_16x16x32_bf16(a0,b0,acc[0],0,0,0);
      acc[1] = __builtin_amdgcn_mfma_f32_16x16x32_bf16(a0,b1,acc[1],0,0,0);
    }
    __syncthreads();
  }
  int cr = (lane>>4)<<2, cc = lane&15;
  #pragma unroll
  for (int jj=0;jj<2;jj++){
    int row = bm + wm + cr;
    int col = bn + wn + (jj<<4) + cc;
    #pragma unroll
    for (int r=0;r<4;r++){
      size_t idx2 = (size_t)(row+r)*DM + col;
      h[idx2] += acc[jj][r];
    }
  }
}

// ---------------- masked pooling: 32 blocks, LDS-staged mask ----------------
__global__ __launch_bounds__(256) void k_pool(const float* __restrict__ h,
    const int* __restrict__ mask, float* __restrict__ partial){
  int p = blockIdx.x, b = blockIdx.y, d = threadIdx.x;
  int t0 = p*64;
  __shared__ float sm[64];
  if (d < 64) sm[d] = (float)mask[b*L_ + t0 + d];
  __syncthreads();
  const float* hp = &h[(size_t)(b*L_ + t0)*DM + d];
  float s = 0.f;
  #pragma unroll 8
  for (int i=0;i<64;i++)
    s = fmaf(sm[i], hp[(size_t)i*DM], s);
  partial[(size_t)(b*16+p)*DM + d] = s;
}

// ---------------- final: count + LN + classifier (1 block/batch) ----------------
__global__ __launch_bounds__(256) void k_head(const float* __restrict__ partial,
    const int* __restrict__ mask, const float* __restrict__ nw, const float* __restrict__ nb,
    const float* __restrict__ cw, const float* __restrict__ cb, float* __restrict__ out){
  int b = blockIdx.x, d = threadIdx.x;
  // mask count: 256 threads x 4 ints
  int4 mi = *reinterpret_cast<const int4*>(&mask[b*L_ + d*4]);
  float cnt = (float)(mi.x + mi.y + mi.z + mi.w);
  #pragma unroll
  for (int o=32;o>0;o>>=1) cnt += __shfl_down(cnt,o);
  __shared__ float ac[4];
  __shared__ float scnt;
  int wid = d>>6, lane = d&63;
  if (lane==0) ac[wid] = cnt;
  __syncthreads();
  if (d==0) scnt = ac[0]+ac[1]+ac[2]+ac[3];
  __syncthreads();
  float s = 0.f;
  #pragma unroll
  for (int p=0;p<16;p++) s += partial[(size_t)(b*16+p)*DM + d];
  float v = s / scnt;
  float s1 = v, s2 = v*v;
  #pragma unroll
  for (int o=32;o>0;o>>=1){ s1 += __shfl_down(s1,o); s2 += __shfl_down(s2,o); }
  __shared__ float a1[4], a2[4];
  __shared__ float mv[2];
  if (lane==0){ a1[wid]=s1; a2[wid]=s2; }
  __syncthreads();
  if (d==0){
    float t1=a1[0]+a1[1]+a1[2]+a1[3];
    float t2=a2[0]+a2[1]+a2[2]+a2[3];
    float m = t1/(float)DM;
    mv[0]=m; mv[1]=rsqrtf(t2/(float)DM - m*m + 1e-5f);
  }
  __syncthreads();
  __shared__ float sp[DM];
  sp[d] = (v-mv[0])*mv[1]*nw[d]+nb[d];
  __syncthreads();
  __shared__ float cpart[NC_][16];
  if (d < NC_*16){
    int c = d>>4, q = d&15;
    float acc = 0.f;
    #pragma unroll
    for (int k=0;k<16;k++) acc = fmaf(sp[q*16+k], cw[(size_t)c*DM+q*16+k], acc);
    cpart[c][q] = acc;
  }
  __syncthreads();
  if (d < NC_){
    float acc = cb[d];
    #pragma unroll
    for (int q=0;q<16;q++) acc += cpart[d][q];
    out[b*NC_+d] = acc;
  }
}

extern "C" void kernel_launch(void* const* d_in, const int* in_sizes, int n_in,
                              void* d_out, int out_size, void* d_ws, size_t ws_size,
                              hipStream_t stream){
  const float* emb   = (const float*)d_in[0];
  const float* pos   = (const float*)d_in[1];
  const float* ln_w  = (const float*)d_in[2];
  const float* ln_b  = (const float*)d_in[3];
  const float* ipw   = (const float*)d_in[4];
  const float* cw    = (const float*)d_in[5];
  const float* cb    = (const float*)d_in[6];
  const float* xpw   = (const float*)d_in[7];
  const float* dtw   = (const float*)d_in[8];
  const float* dtb   = (const float*)d_in[9];
  const float* A_log = (const float*)d_in[10];
  const float* Dp    = (const float*)d_in[11];
  const float* opw   = (const float*)d_in[12];
  const float* nw    = (const float*)d_in[13];
  const float* nb    = (const float*)d_in[14];
  const float* clw   = (const float*)d_in[15];
  const float* clb   = (const float*)d_in[16];
  const int*   ids   = (const int*)d_in[17];
  const int*   mask  = (const int*)d_in[18];
  float* out = (float*)d_out;

  float* ws    = (float*)d_ws;
  float* h     = ws;                    // 2048*256
  float* xc    = h + 524288;            // 2048*512
  float* xdbl  = xc + 1048576;          // 2048*48
  float* delta = xdbl + 98304;          // 2048*512
  float* cpA   = delta + 1048576;       // 32*16384
  float* slocA = cpA + 524288;
  float* hlocA = slocA + 524288;
  float* part  = hlocA + 524288;        // 2*16*256
  ushort_t* xzb  = (ushort_t*)(part + 8192);     // 2048*1024 bf16
  ushort_t* y2b  = xzb + 2097152;                // 2048*512 bf16
  ushort_t* ipwb = y2b + 1048576;                // 6*1024*256 bf16
  ushort_t* opwb = ipwb + 1572864;               // 6*256*512 bf16

  k_cvt<<<dim3(1536), 256, 0, stream>>>(ipw, ipwb, 6*2*DI_*DM);
  k_cvt<<<dim3(768),  256, 0, stream>>>(opw, opwb, 6*DM*DI_);
  k_embed<<<dim3(B_*L_), dim3(DM), 0, stream>>>(emb, pos, ids, h);

  for (int l=0; l<NL_; ++l){
    k_gemm_ln<<<dim3(16, 32), 256, 0, stream>>>(
        h, ipwb + (size_t)l*2*DI_*DM, ln_w + l*DM, ln_b + l*DM, xzb);
    k_xpc<<<dim3((B_*L_)/4), 256, 0, stream>>>(
        xzb, cw + l*DI_*DC_, cb + l*DI_, xpw + (size_t)l*48*DI_,
        dtw + (size_t)l*DI_*16, dtb + l*DI_, xc, xdbl, delta);
    k_scanA<<<dim3(NCH, DI_/16, B_), 256, 0, stream>>>(
        delta, xc, xdbl, A_log + (size_t)l*DI_*DS_, cpA, slocA, hlocA);
    k_scanC<<<dim3(NCH, DI_/16, B_), 256, 0, stream>>>(
        delta, xc, xdbl, xzb, A_log + (size_t)l*DI_*DS_, Dp + l*DI_,
        cpA, slocA, hlocA, y2b);
    k_gemm_out<<<dim3(DM/64, (B_*L_)/32), 256, 0, stream>>>(
        y2b, opwb + (size_t)l*DM*DI_, h);
  }
  k_pool<<<dim3(16, B_), 256, 0, stream>>>(h, mask, part);
  k_head<<<dim3(B_), 256, 0, stream>>>(part, mask, nw, nb, clw, clb, out);
}

// Round 6
// 477.271 us; speedup vs baseline: 4.3888x; 1.0037x over previous
//
#include <hip/hip_runtime.h>
#include <math.h>

#define B_ 2
#define L_ 1024
#define DM 256
#define NL_ 6
#define DI_ 512
#define DS_ 16
#define DC_ 4
#define NC_ 10
#define ALPHA_ 0.1f
#define LC 32
#define NCH (L_/LC)            // 32 chunks
#define NCHAIN (B_*DI_*DS_)    // 16384 chains
#define BETA_LC 0.034336838202925124f  // 0.9^32

typedef unsigned short ushort_t;
typedef __attribute__((ext_vector_type(8))) short s16x8;      // 8 bf16 (MFMA A/B frag)
typedef __attribute__((ext_vector_type(4))) float f32x4;      // MFMA C/D frag
typedef __attribute__((ext_vector_type(8))) unsigned short u16x8;

__device__ __forceinline__ float sigmoidf_(float x){ return 1.f/(1.f+__expf(-x)); }
__device__ __forceinline__ ushort_t f2bf(float f){
  union{float f;unsigned u;} c; c.f=f; unsigned u=c.u;
  return (ushort_t)((u + 0x7fffu + ((u>>16)&1u))>>16);
}
__device__ __forceinline__ float bf2f(ushort_t h){
  union{unsigned u;float f;} c; c.u = ((unsigned)h)<<16; return c.f;
}
// stagger-pad index for sx: insert 4-word gap every 128 words (bank-conflict fix)
__device__ __forceinline__ int kidx(int d){ return d + ((d>>7)<<2); }

// ---------------- embed ----------------
__global__ void k_embed(const float* __restrict__ emb, const float* __restrict__ pos,
                        const int* __restrict__ ids, float* __restrict__ h){
  int row = blockIdx.x;
  int t = row & (L_-1);
  int d = threadIdx.x;
  int v = ids[row];
  h[(size_t)row*DM + d] = emb[(size_t)v*DM + d] + pos[(size_t)t*DM + d];
}

// ---------------- fp32 -> bf16 weight conversion (both weight sets, one launch) ----------------
__global__ void k_cvt2(const float* __restrict__ a, int na, const float* __restrict__ b2,
                       ushort_t* __restrict__ oa, ushort_t* __restrict__ ob, int ntot){
  int i = (blockIdx.x*256 + threadIdx.x)*4;
  if (i >= ntot) return;
  const float* src; ushort_t* dst; int k;
  if (i < na){ src = a; dst = oa; k = i; }
  else       { src = b2; dst = ob; k = i - na; }
  float4 v = *reinterpret_cast<const float4*>(&src[k]);
  ushort4 r;
  r.x = f2bf(v.x); r.y = f2bf(v.y); r.z = f2bf(v.z); r.w = f2bf(v.w);
  *reinterpret_cast<ushort4*>(&dst[k]) = r;
}

// ---------------- fused LN + in_proj GEMM (bf16 MFMA), writes xz bf16 ----------------
__global__ __launch_bounds__(256) void k_gemm_ln(const float* __restrict__ h,
    const ushort_t* __restrict__ W, const float* __restrict__ lw,
    const float* __restrict__ lb, ushort_t* __restrict__ xzb){
  __shared__ ushort_t As[64][264];   // 256 + 8 pad -> 2-way bank alias (free)
  __shared__ ushort_t Ws[64][264];
  int bm = blockIdx.y<<6, bn = blockIdx.x<<6;
  int tid = threadIdx.x;
  {
    int r = tid>>2, q = tid&3;       // 4 threads per row, 64 elems each
    const float* src = &h[(size_t)(bm+r)*DM + q*64];
    float4 v[16]; float s1=0.f, s2=0.f;
    #pragma unroll
    for (int i=0;i<16;i++){
      v[i] = *reinterpret_cast<const float4*>(src + i*4);
      s1 += v[i].x+v[i].y+v[i].z+v[i].w;
      s2 += v[i].x*v[i].x+v[i].y*v[i].y+v[i].z*v[i].z+v[i].w*v[i].w;
    }
    s1 += __shfl_xor(s1,1); s2 += __shfl_xor(s2,1);
    s1 += __shfl_xor(s1,2); s2 += __shfl_xor(s2,2);
    float mean = s1*(1.f/DM);
    float rstd = rsqrtf(s2*(1.f/DM) - mean*mean + 1e-5f);
    #pragma unroll
    for (int i=0;i<16;i++){
      int c = q*64 + i*4;
      ushort4 o;
      o.x = f2bf((v[i].x-mean)*rstd*lw[c+0]+lb[c+0]);
      o.y = f2bf((v[i].y-mean)*rstd*lw[c+1]+lb[c+1]);
      o.z = f2bf((v[i].z-mean)*rstd*lw[c+2]+lb[c+2]);
      o.w = f2bf((v[i].w-mean)*rstd*lw[c+3]+lb[c+3]);
      *reinterpret_cast<ushort4*>(&As[r][c]) = o;
    }
    const ushort_t* ws = &W[(size_t)(bn+r)*DM + q*64];
    #pragma unroll
    for (int i=0;i<8;i++)
      *reinterpret_cast<u16x8*>(&Ws[r][q*64+i*8]) = *reinterpret_cast<const u16x8*>(ws + i*8);
  }
  __syncthreads();
  int lane = tid&63, wid = tid>>6;
  int wm = (wid>>1)<<5, wn = (wid&1)<<5;
  int fr = lane&15, fk = (lane>>4)<<3;
  f32x4 acc[2][2] = {};
  #pragma unroll
  for (int k0=0;k0<DM;k0+=32){
    s16x8 a0 = *reinterpret_cast<const s16x8*>(&As[wm+fr][k0+fk]);
    s16x8 a1 = *reinterpret_cast<const s16x8*>(&As[wm+16+fr][k0+fk]);
    s16x8 b0 = *reinterpret_cast<const s16x8*>(&Ws[wn+fr][k0+fk]);
    s16x8 b1 = *reinterpret_cast<const s16x8*>(&Ws[wn+16+fr][k0+fk]);
    acc[0][0] = __builtin_amdgcn_mfma_f32_16x16x32_bf16(a0,b0,acc[0][0],0,0,0);
    acc[0][1] = __builtin_amdgcn_mfma_f32_16x16x32_bf16(a0,b1,acc[0][1],0,0,0);
    acc[1][0] = __builtin_amdgcn_mfma_f32_16x16x32_bf16(a1,b0,acc[1][0],0,0,0);
    acc[1][1] = __builtin_amdgcn_mfma_f32_16x16x32_bf16(a1,b1,acc[1][1],0,0,0);
  }
  int cr = (lane>>4)<<2, cc = lane&15;
  #pragma unroll
  for (int i=0;i<2;i++)
    #pragma unroll
    for (int j=0;j<2;j++){
      int row = bm + wm + (i<<4) + cr;
      int col = bn + wn + (j<<4) + cc;
      #pragma unroll
      for (int r=0;r<4;r++)
        xzb[(size_t)(row+r)*(2*DI_) + col] = f2bf(acc[i][j][r]);
    }
}

// ---------------- fused conv+SiLU + x_proj + dt_proj + softplus (4 rows/block) ----------------
// writes xc (bf16), xdbl (fp32), delta (bf16)
__global__ __launch_bounds__(256) void k_xpc(const ushort_t* __restrict__ xzb,
    const float* __restrict__ cw, const float* __restrict__ cb,
    const float* __restrict__ xw, const float* __restrict__ dtw,
    const float* __restrict__ dtb, ushort_t* __restrict__ xcb,
    float* __restrict__ xdbl, ushort_t* __restrict__ deltab){
  __shared__ float sxz[7][DI_];
  __shared__ float sx[4][DI_+16];    // stagger-padded: kidx(d)
  __shared__ float sdbl[4][48];
  int tid = threadIdx.x;
  int m0 = blockIdx.x*4;
  #pragma unroll
  for (int idx=0; idx<14; ++idx){
    int flat = idx*256 + tid;            // 7*512 = 3584
    int i = flat>>9, d = flat&511;
    int mr = m0 - 3 + i;
    sxz[i][d] = (mr>=0) ? bf2f(xzb[(size_t)mr*(2*DI_) + d]) : 0.f;
  }
  __syncthreads();
  #pragma unroll
  for (int idx=0; idx<8; ++idx){
    int flat = idx*256 + tid;            // 4*512 = 2048
    int r = flat>>9, d = flat&511;
    int t = (m0 + r) & (L_-1);
    float acc = cb[d];
    #pragma unroll
    for (int k=0;k<4;k++)
      if (t-3+k >= 0) acc = fmaf(cw[d*4+k], sxz[r+k][d], acc);
    float sv = acc * sigmoidf_(acc);
    sx[r][kidx(d)] = sv;
    xcb[(size_t)(m0+r)*DI_ + d] = f2bf(sv);
  }
  __syncthreads();
  if (tid < 192){
    int o = tid>>2, q = tid&3;           // 48 outputs x 4 K-quarters
    const float* wp = &xw[(size_t)o*DI_ + q*128];
    const int qb = q*132;                // padded quarter base (conflict-free)
    float a0=0.f,a1=0.f,a2=0.f,a3=0.f;
    #pragma unroll 8
    for (int k4=0;k4<32;k4++){
      float4 wv = *reinterpret_cast<const float4*>(wp + k4*4);
      int kk = qb + k4*4;
      float4 x0 = *reinterpret_cast<const float4*>(&sx[0][kk]);
      float4 x1 = *reinterpret_cast<const float4*>(&sx[1][kk]);
      float4 x2 = *reinterpret_cast<const float4*>(&sx[2][kk]);
      float4 x3 = *reinterpret_cast<const float4*>(&sx[3][kk]);
      a0 = fmaf(x0.x,wv.x,a0); a0 = fmaf(x0.y,wv.y,a0); a0 = fmaf(x0.z,wv.z,a0); a0 = fmaf(x0.w,wv.w,a0);
      a1 = fmaf(x1.x,wv.x,a1); a1 = fmaf(x1.y,wv.y,a1); a1 = fmaf(x1.z,wv.z,a1); a1 = fmaf(x1.w,wv.w,a1);
      a2 = fmaf(x2.x,wv.x,a2); a2 = fmaf(x2.y,wv.y,a2); a2 = fmaf(x2.z,wv.z,a2); a2 = fmaf(x2.w,wv.w,a2);
      a3 = fmaf(x3.x,wv.x,a3); a3 = fmaf(x3.y,wv.y,a3); a3 = fmaf(x3.z,wv.z,a3); a3 = fmaf(x3.w,wv.w,a3);
    }
    a0 += __shfl_xor(a0,1); a0 += __shfl_xor(a0,2);
    a1 += __shfl_xor(a1,1); a1 += __shfl_xor(a1,2);
    a2 += __shfl_xor(a2,1); a2 += __shfl_xor(a2,2);
    a3 += __shfl_xor(a3,1); a3 += __shfl_xor(a3,2);
    if (q==0){
      sdbl[0][o]=a0; sdbl[1][o]=a1; sdbl[2][o]=a2; sdbl[3][o]=a3;
      xdbl[(size_t)(m0+0)*48+o]=a0;
      xdbl[(size_t)(m0+1)*48+o]=a1;
      xdbl[(size_t)(m0+2)*48+o]=a2;
      xdbl[(size_t)(m0+3)*48+o]=a3;
    }
  }
  __syncthreads();
  #pragma unroll
  for (int idx=0; idx<8; ++idx){
    int flat = idx*256 + tid;
    int r = flat>>9, n = flat&511;
    const float4* wp = reinterpret_cast<const float4*>(&dtw[n*16]);
    float4 w0=wp[0], w1=wp[1], w2=wp[2], w3=wp[3];
    const float* sd = sdbl[r];
    float acc = dtb[n];
    acc = fmaf(sd[0],w0.x,acc);  acc = fmaf(sd[1],w0.y,acc);
    acc = fmaf(sd[2],w0.z,acc);  acc = fmaf(sd[3],w0.w,acc);
    acc = fmaf(sd[4],w1.x,acc);  acc = fmaf(sd[5],w1.y,acc);
    acc = fmaf(sd[6],w1.z,acc);  acc = fmaf(sd[7],w1.w,acc);
    acc = fmaf(sd[8],w2.x,acc);  acc = fmaf(sd[9],w2.y,acc);
    acc = fmaf(sd[10],w2.z,acc); acc = fmaf(sd[11],w2.w,acc);
    acc = fmaf(sd[12],w3.x,acc); acc = fmaf(sd[13],w3.y,acc);
    acc = fmaf(sd[14],w3.z,acc); acc = fmaf(sd[15],w3.w,acc);
    float sp2 = (acc>20.f)? acc : log1pf(__expf(acc));
    deltab[(size_t)(m0+r)*DI_ + n] = f2bf(sp2);
  }
}

// ================= chunked parallel scan (LC=32) =================
// Pass A: per-chunk summary {cp, hs_loc, hh_loc} packed in float4
__global__ __launch_bounds__(256) void k_scanA(const ushort_t* __restrict__ deltab,
    const ushort_t* __restrict__ xcb, const float* __restrict__ xdbl,
    const float* __restrict__ A_log, float4* __restrict__ smry){
  int j = blockIdx.x, g = blockIdx.y, b = blockIdx.z;
  int tid = threadIdx.x;
  int n = tid&15, dg = tid>>4;
  int d0 = g*16;
  __shared__ float sdel[LC][16], sxv[LC][16], sB[LC][16];
  if (tid < 128){
    int arr = tid>>6, slot = tid&63, row = slot>>1, half = slot&1;
    int m = b*L_ + j*LC + row;
    const ushort_t* src = arr ? xcb : deltab;
    u16x8 v = *reinterpret_cast<const u16x8*>(&src[(size_t)m*DI_ + d0 + half*8]);
    float* dst = arr ? &sxv[row][half*8] : &sdel[row][half*8];
    #pragma unroll
    for (int i=0;i<8;i++) dst[i] = bf2f((ushort_t)v[i]);
  } else {
    int slot = tid-128;                 // 128 float4 tasks for sB
    int row = slot>>2, c4 = (slot&3)<<2;
    int m = b*L_ + j*LC + row;
    *reinterpret_cast<float4*>(&sB[row][c4]) =
      *reinterpret_cast<const float4*>(&xdbl[(size_t)m*48 + 16 + c4]);
  }
  __syncthreads();
  float a = -__expf(A_log[(d0+dg)*DS_ + n]);
  float hs=0.f, hh=0.f, cp=1.f;
  #pragma unroll
  for (int tt=0; tt<LC; tt+=8){
    float dA8[8], dBu8[8];
    #pragma unroll
    for (int t=0;t<8;t++){
      float dv = sdel[tt+t][dg];
      dA8[t]  = __expf(dv*a);
      dBu8[t] = dv * sxv[tt+t][dg] * sB[tt+t][n];
    }
    #pragma unroll
    for (int t=0;t<8;t++){
      float mix = fmaf(ALPHA_, hs-hh, hh);
      hs = fmaf(dA8[t], hs, dBu8[t]);
      hh = fmaf(dA8[t], mix, dBu8[t]);
      cp *= dA8[t];
    }
  }
  smry[(size_t)j*NCHAIN + (size_t)(b*DI_+d0)*DS_ + tid] = float4{cp,hs,hh,0.f};
}

// Pass C: inline lookback + re-run + gate, writes y2 bf16
__global__ __launch_bounds__(256) void k_scanC(const ushort_t* __restrict__ deltab,
    const ushort_t* __restrict__ xcb, const float* __restrict__ xdbl,
    const ushort_t* __restrict__ xzb, const float* __restrict__ A_log,
    const float* __restrict__ Dp, const float4* __restrict__ smry,
    ushort_t* __restrict__ y2b){
  int j = blockIdx.x, g = blockIdx.y, b = blockIdx.z;
  int tid = threadIdx.x;
  int n = tid&15, dg = tid>>4;
  int d0 = g*16;
  __shared__ float sdel[LC][16], sxv[LC][16], sB[LC][16], sC[LC][16], sz[LC][16], sy[LC][16];
  if (tid < 128){
    int arr = tid>>6, slot = tid&63, row = slot>>1, half = slot&1;
    int m = b*L_ + j*LC + row;
    const ushort_t* src = arr ? xcb : deltab;
    u16x8 v = *reinterpret_cast<const u16x8*>(&src[(size_t)m*DI_ + d0 + half*8]);
    float* dst = arr ? &sxv[row][half*8] : &sdel[row][half*8];
    #pragma unroll
    for (int i=0;i<8;i++) dst[i] = bf2f((ushort_t)v[i]);
  } else if (tid < 192){
    int slot = tid-128, row = slot>>1, half = slot&1;
    int m = b*L_ + j*LC + row;
    u16x8 v = *reinterpret_cast<const u16x8*>(&xzb[(size_t)m*(2*DI_) + DI_ + d0 + half*8]);
    #pragma unroll
    for (int i=0;i<8;i++) sz[row][half*8+i] = bf2f((ushort_t)v[i]);
  } else {
    int slot = tid-192;                 // 64 threads x 4 float4 tasks for sB+sC
    #pragma unroll
    for (int k=0;k<4;k++){
      int t4 = slot + k*64;             // 256 tasks: 2 arrays x 128 float4
      int arr = t4>>7, idx4 = t4&127;
      int row = idx4>>2, c4 = (idx4&3)<<2;
      int m = b*L_ + j*LC + row;
      float* dst = arr ? &sC[row][c4] : &sB[row][c4];
      *reinterpret_cast<float4*>(dst) =
        *reinterpret_cast<const float4*>(&xdbl[(size_t)m*48 + 16 + arr*16 + c4]);
    }
  }
  // inline lookback over chunks 0..j-1 (one float4 load per step)
  int chain = (b*DI_+d0)*DS_ + tid;
  float hs=0.f, hh=0.f;
  #pragma unroll 4
  for (int jj=0; jj<j; ++jj){
    float4 v = smry[(size_t)jj*NCHAIN + chain];
    float snew = fmaf(v.x, hs, v.y);
    hh = fmaf(v.x, fmaf(BETA_LC, hh-hs, hs), v.z);
    hs = snew;
  }
  __syncthreads();
  float a = -__expf(A_log[(d0+dg)*DS_ + n]);
  #pragma unroll
  for (int tt=0; tt<LC; tt+=8){
    float dA8[8], dBu8[8], yv8[8];
    #pragma unroll
    for (int t=0;t<8;t++){
      float dv = sdel[tt+t][dg];
      dA8[t]  = __expf(dv*a);
      dBu8[t] = dv * sxv[tt+t][dg] * sB[tt+t][n];
    }
    #pragma unroll
    for (int t=0;t<8;t++){
      float mix = fmaf(ALPHA_, hs-hh, hh);
      hs = fmaf(dA8[t], hs, dBu8[t]);
      hh = fmaf(dA8[t], mix, dBu8[t]);
      yv8[t] = hh * sC[tt+t][n];
    }
    #pragma unroll
    for (int t=0;t<8;t++){
      yv8[t] += __shfl_xor(yv8[t],1,16);
      yv8[t] += __shfl_xor(yv8[t],2,16);
      yv8[t] += __shfl_xor(yv8[t],4,16);
      yv8[t] += __shfl_xor(yv8[t],8,16);
    }
    if (n==0){
      #pragma unroll
      for (int t=0;t<8;t++) sy[tt+t][dg] = yv8[t];
    }
  }
  __syncthreads();
  float dpv = Dp[d0 + (tid&15)];
  #pragma unroll
  for (int idx=0; idx<2; ++idx){
    int flat = idx*256 + tid;
    int t2 = flat>>4, dd = flat&15;
    float xvv = sxv[t2][dd];
    float zv  = sz [t2][dd];
    float yfin = (sy[t2][dd] + dpv*xvv) * (zv*sigmoidf_(zv));
    y2b[(size_t)(b*L_ + j*LC + t2)*DI_ + d0 + dd] = f2bf(yfin);
  }
}

// ---------------- out_proj GEMM (bf16 MFMA) + residual, h += y2 @ W^T ----------------
__global__ __launch_bounds__(256) void k_gemm_out(const ushort_t* __restrict__ A,
    const ushort_t* __restrict__ W, float* __restrict__ h){
  __shared__ ushort_t As[32][264];
  __shared__ ushort_t Ws[64][264];
  int bm = blockIdx.y<<5, bn = blockIdx.x<<6;
  int tid = threadIdx.x;
  int lane = tid&63, wid = tid>>6;
  int wm = (wid>>1)<<4, wn = (wid&1)<<5;
  int fr = lane&15, fk = (lane>>4)<<3;
  f32x4 acc[2] = {};
  for (int k0=0;k0<DI_;k0+=256){
    {
      int r = tid>>3, q = tid&7;
      const ushort_t* src = &A[(size_t)(bm+r)*DI_ + k0 + q*32];
      #pragma unroll
      for (int i=0;i<4;i++)
        *reinterpret_cast<u16x8*>(&As[r][q*32+i*8]) = *reinterpret_cast<const u16x8*>(src+i*8);
      int r2 = tid>>2, q2 = tid&3;
      const ushort_t* ws = &W[(size_t)(bn+r2)*DI_ + k0 + q2*64];
      #pragma unroll
      for (int i=0;i<8;i++)
        *reinterpret_cast<u16x8*>(&Ws[r2][q2*64+i*8]) = *reinterpret_cast<const u16x8*>(ws+i*8);
    }
    __syncthreads();
    #pragma unroll
    for (int k=0;k<256;k+=32){
      s16x8 a0 = *reinterpret_cast<const s16x8*>(&As[wm+fr][k+fk]);
      s16x8 b0 = *reinterpret_cast<const s16x8*>(&Ws[wn+fr][k+fk]);
      s16x8 b1 = *reinterpret_cast<const s16x8*>(&Ws[wn+16+fr][k+fk]);
      acc[0] = __builtin_amdgcn_mfma_f32_16x16x32_bf16(a0,b0,acc[0],0,0,0);
      acc[1] = __builtin_amdgcn_mfma_f32_16x16x32_bf16(a0,b1,acc[1],0,0,0);
    }
    __syncthreads();
  }
  int cr = (lane>>4)<<2, cc = lane&15;
  #pragma unroll
  for (int jj=0;jj<2;jj++){
    int row = bm + wm + cr;
    int col = bn + wn + (jj<<4) + cc;
    #pragma unroll
    for (int r=0;r<4;r++){
      size_t idx2 = (size_t)(row+r)*DM + col;
      h[idx2] += acc[jj][r];
    }
  }
}

// ---------------- masked pooling: 32 blocks, LDS-staged mask ----------------
__global__ __launch_bounds__(256) void k_pool(const float* __restrict__ h,
    const int* __restrict__ mask, float* __restrict__ partial){
  int p = blockIdx.x, b = blockIdx.y, d = threadIdx.x;
  int t0 = p*64;
  __shared__ float sm[64];
  if (d < 64) sm[d] = (float)mask[b*L_ + t0 + d];
  __syncthreads();
  const float* hp = &h[(size_t)(b*L_ + t0)*DM + d];
  float s = 0.f;
  #pragma unroll 8
  for (int i=0;i<64;i++)
    s = fmaf(sm[i], hp[(size_t)i*DM], s);
  partial[(size_t)(b*16+p)*DM + d] = s;
}

// ---------------- final: count + LN + classifier (1 block/batch) ----------------
__global__ __launch_bounds__(256) void k_head(const float* __restrict__ partial,
    const int* __restrict__ mask, const float* __restrict__ nw, const float* __restrict__ nb,
    const float* __restrict__ cw, const float* __restrict__ cb, float* __restrict__ out){
  int b = blockIdx.x, d = threadIdx.x;
  int4 mi = *reinterpret_cast<const int4*>(&mask[b*L_ + d*4]);
  float cnt = (float)(mi.x + mi.y + mi.z + mi.w);
  #pragma unroll
  for (int o=32;o>0;o>>=1) cnt += __shfl_down(cnt,o);
  __shared__ float ac[4];
  __shared__ float scnt;
  int wid = d>>6, lane = d&63;
  if (lane==0) ac[wid] = cnt;
  __syncthreads();
  if (d==0) scnt = ac[0]+ac[1]+ac[2]+ac[3];
  __syncthreads();
  float s = 0.f;
  #pragma unroll
  for (int p=0;p<16;p++) s += partial[(size_t)(b*16+p)*DM + d];
  float v = s / scnt;
  float s1 = v, s2 = v*v;
  #pragma unroll
  for (int o=32;o>0;o>>=1){ s1 += __shfl_down(s1,o); s2 += __shfl_down(s2,o); }
  __shared__ float a1[4], a2[4];
  __shared__ float mv[2];
  if (lane==0){ a1[wid]=s1; a2[wid]=s2; }
  __syncthreads();
  if (d==0){
    float t1=a1[0]+a1[1]+a1[2]+a1[3];
    float t2=a2[0]+a2[1]+a2[2]+a2[3];
    float m = t1/(float)DM;
    mv[0]=m; mv[1]=rsqrtf(t2/(float)DM - m*m + 1e-5f);
  }
  __syncthreads();
  __shared__ float sp[DM];
  sp[d] = (v-mv[0])*mv[1]*nw[d]+nb[d];
  __syncthreads();
  __shared__ float cpart[NC_][16];
  if (d < NC_*16){
    int c = d>>4, q = d&15;
    float acc = 0.f;
    #pragma unroll
    for (int k=0;k<16;k++) acc = fmaf(sp[q*16+k], cw[(size_t)c*DM+q*16+k], acc);
    cpart[c][q] = acc;
  }
  __syncthreads();
  if (d < NC_){
    float acc = cb[d];
    #pragma unroll
    for (int q=0;q<16;q++) acc += cpart[d][q];
    out[b*NC_+d] = acc;
  }
}

extern "C" void kernel_launch(void* const* d_in, const int* in_sizes, int n_in,
                              void* d_out, int out_size, void* d_ws, size_t ws_size,
                              hipStream_t stream){
  const float* emb   = (const float*)d_in[0];
  const float* pos   = (const float*)d_in[1];
  const float* ln_w  = (const float*)d_in[2];
  const float* ln_b  = (const float*)d_in[3];
  const float* ipw   = (const float*)d_in[4];
  const float* cw    = (const float*)d_in[5];
  const float* cb    = (const float*)d_in[6];
  const float* xpw   = (const float*)d_in[7];
  const float* dtw   = (const float*)d_in[8];
  const float* dtb   = (const float*)d_in[9];
  const float* A_log = (const float*)d_in[10];
  const float* Dp    = (const float*)d_in[11];
  const float* opw   = (const float*)d_in[12];
  const float* nw    = (const float*)d_in[13];
  const float* nb    = (const float*)d_in[14];
  const float* clw   = (const float*)d_in[15];
  const float* clb   = (const float*)d_in[16];
  const int*   ids   = (const int*)d_in[17];
  const int*   mask  = (const int*)d_in[18];
  float* out = (float*)d_out;

  float* ws    = (float*)d_ws;
  float* h     = ws;                    // 2048*256
  float* xdbl  = h + 524288;            // 2048*48
  float* part  = xdbl + 98304;          // 2*16*256
  float4* smry = (float4*)(part + 8192);// 32*16384 float4 = 2097152 floats
  ushort_t* xzb    = (ushort_t*)((float*)smry + 2097152); // 2048*1024 bf16
  ushort_t* xcb    = xzb + 2097152;     // 2048*512 bf16
  ushort_t* deltab = xcb + 1048576;     // 2048*512 bf16
  ushort_t* y2b    = deltab + 1048576;  // 2048*512 bf16
  ushort_t* ipwb   = y2b + 1048576;     // 6*1024*256 bf16
  ushort_t* opwb   = ipwb + 1572864;    // 6*256*512 bf16

  const int NA = 6*2*DI_*DM, NB = 6*DM*DI_;
  k_cvt2<<<dim3((NA+NB)/1024), 256, 0, stream>>>(ipw, NA, opw, ipwb, opwb, NA+NB);
  k_embed<<<dim3(B_*L_), dim3(DM), 0, stream>>>(emb, pos, ids, h);

  for (int l=0; l<NL_; ++l){
    k_gemm_ln<<<dim3(16, 32), 256, 0, stream>>>(
        h, ipwb + (size_t)l*2*DI_*DM, ln_w + l*DM, ln_b + l*DM, xzb);
    k_xpc<<<dim3((B_*L_)/4), 256, 0, stream>>>(
        xzb, cw + l*DI_*DC_, cb + l*DI_, xpw + (size_t)l*48*DI_,
        dtw + (size_t)l*DI_*16, dtb + l*DI_, xcb, xdbl, deltab);
    k_scanA<<<dim3(NCH, DI_/16, B_), 256, 0, stream>>>(
        deltab, xcb, xdbl, A_log + (size_t)l*DI_*DS_, smry);
    k_scanC<<<dim3(NCH, DI_/16, B_), 256, 0, stream>>>(
        deltab, xcb, xdbl, xzb, A_log + (size_t)l*DI_*DS_, Dp + l*DI_,
        smry, y2b);
    k_gemm_out<<<dim3(DM/64, (B_*L_)/32), 256, 0, stream>>>(
        y2b, opwb + (size_t)l*DM*DI_, h);
  }
  k_pool<<<dim3(16, B_), 256, 0, stream>>>(h, mask, part);
  k_head<<<dim3(B_), 256, 0, stream>>>(part, mask, nw, nb, clw, clb, out);
}